// Round 6
// baseline (2572.235 us; speedup 1.0000x reference)
//
#include <hip/hip_runtime.h>

#define N_NODES 50000
#define N_PAD   50048   // multiple of 64; pad rows garbage, never consumed
#define N_EDGES 800000
#define N_GRAPHS 500
#define DIM 128
#define EDIM 7
#define LAYERS 5
#define NCLASS 10
#define BN_EPS 1e-5f
#define TM 64
#define AST 264         // LDS A row stride (ushort): 528 B = odd 16B multiple -> conflict-free b128
#define NTILES (N_PAD / TM)    // 782
#define NGRP (N_NODES / 8)     // 6250 node-groups (8 nodes per 256-thr pass)

typedef __attribute__((ext_vector_type(8))) short bf16x8;
typedef __attribute__((ext_vector_type(4))) float f32x4;

__device__ __forceinline__ unsigned short f2bf(float f) {
    unsigned u = __float_as_uint(f);
    u = u + 0x7fffu + ((u >> 16) & 1u);   // RNE
    return (unsigned short)(u >> 16);
}
__device__ __forceinline__ float bf2f(unsigned short h) {
    return __uint_as_float(((unsigned)h) << 16);
}

// ---------------- CSR build (standalone pre-kernels) ----------------

__global__ void zero_ints(int* __restrict__ p, int n) {
    int i = blockIdx.x * 256 + threadIdx.x;
    if (i < n) p[i] = 0;
}

__global__ void hist_kernel(const int* __restrict__ dst, int* __restrict__ deg) {
    int e = blockIdx.x * 256 + threadIdx.x;
    if (e < N_EDGES) atomicAdd(&deg[dst[e]], 1);
}

__global__ void scan_kernel(const int* __restrict__ deg, int* __restrict__ row_off) {
    __shared__ int wsum[16];
    __shared__ int carry;
    int t = threadIdx.x;
    int lane = t & 63, wid = t >> 6;
    if (t == 0) carry = 0;
    __syncthreads();
    for (int base = 0; base < N_NODES; base += 1024) {
        int i = base + t;
        int v = (i < N_NODES) ? deg[i] : 0;
        int s = v;
        #pragma unroll
        for (int off = 1; off < 64; off <<= 1) {
            int u = __shfl_up(s, off, 64);
            if (lane >= off) s += u;
        }
        if (lane == 63) wsum[wid] = s;
        __syncthreads();
        if (wid == 0) {
            int ws = (lane < 16) ? wsum[lane] : 0;
            int ss = ws;
            #pragma unroll
            for (int off2 = 1; off2 < 16; off2 <<= 1) {
                int u = __shfl_up(ss, off2, 64);
                if (lane >= off2) ss += u;
            }
            if (lane < 16) wsum[lane] = ss - ws;
        }
        __syncthreads();
        int incl = s + wsum[wid];
        int excl = incl - v;
        if (i < N_NODES) row_off[i] = carry + excl;
        __syncthreads();
        if (t == 1023) carry += incl;
        __syncthreads();
    }
    if (t == 0) row_off[N_NODES] = carry;
}

__global__ void fill_csr(const int* __restrict__ dst, const int* __restrict__ row_off,
                         int* __restrict__ cursor, int* __restrict__ csr_edges) {
    int e = blockIdx.x * 256 + threadIdx.x;
    if (e < N_EDGES) {
        int d = dst[e];
        int pos = atomicAdd(&cursor[d], 1);
        csr_edges[row_off[d] + pos] = e;
    }
}

// ---------------- one-time preps ----------------

__global__ void init_x(float* __restrict__ x, unsigned short* __restrict__ xb,
                       const float* __restrict__ emb) {
    int i = blockIdx.x * 256 + threadIdx.x;
    if (i < N_NODES * DIM) {
        float v = emb[i & (DIM - 1)];
        x[i] = v;
        xb[i] = f2bf(v);
    }
}

__global__ void prep_ea(const float* __restrict__ ea, unsigned short* __restrict__ ea8) {
    int i = blockIdx.x * 256 + threadIdx.x;
    if (i < N_EDGES * 8) {
        int e = i >> 3, k = i & 7;
        float v = (k < EDIM) ? ea[e * EDIM + k] : 0.f;
        ea8[i] = f2bf(v);
    }
}

// W [k][n] fp32 -> transposed hi/lo bf16 Wt[m][n][k]
__global__ void prep_w(const float* __restrict__ W1, const float* __restrict__ W2,
                       unsigned short* __restrict__ Wthi, unsigned short* __restrict__ Wtlo) {
    int i = blockIdx.x * 256 + threadIdx.x;
    if (i >= 2 * LAYERS * DIM * DIM) return;
    int m = i >> 14;
    int n = i & 127;
    int k = (i >> 7) & 127;
    const float* W = (m < LAYERS) ? (W1 + (size_t)m * DIM * DIM)
                                  : (W2 + (size_t)(m - LAYERS) * DIM * DIM);
    float v = W[k * DIM + n];
    unsigned short hi = f2bf(v);
    float lo = v - bf2f(hi);
    size_t o = ((size_t)m << 14) + (size_t)n * DIM + k;
    Wthi[o] = hi;
    Wtlo[o] = f2bf(lo);
}

// ---------------- fused kernel ----------------

struct FParams {
    const int* batch;
    const float* edge_W; const float* edge_b;
    const float* mlp_b1; const float* bn1_g; const float* bn1_b; const float* bn1_m; const float* bn1_v;
    const float* mlp_b2; const float* bn2_g; const float* bn2_b; const float* bn2_m; const float* bn2_v;
    const float* head_W1; const float* head_b1; const float* head_W2; const float* head_b2;
    float* x; unsigned short* xb; float* h;
    const unsigned short* ea8;
    const unsigned short* Wthi; const unsigned short* Wtlo;
    const int* src; const int* csr; const int* row_off;
    int* bar;        // monotone grid-barrier counter (pre-zeroed)
    float* out;
};

// Grid barrier: monotone counter, device-scope atomics, fences per ROCm grid.sync pattern.
// Requires all blocks co-resident (guaranteed by occupancy-query-sized grid).
__device__ __forceinline__ void gbar(int* cnt, int target) {
    __syncthreads();
    if (threadIdx.x == 0) {
        __threadfence();                 // release: make this block's writes visible
        atomicAdd(cnt, 1);
        while (atomicAdd(cnt, 0) < target) __builtin_amdgcn_s_sleep(2);
        __threadfence();                 // acquire: invalidate L1/L2 before consuming
    }
    __syncthreads();
}

__device__ __forceinline__ void edge_accum(float4& acc, uint4 eav, uint2 xv,
                                           const float4* Wr, const float4& bd) {
    float a0 = __uint_as_float(eav.x << 16);
    float a1 = __uint_as_float(eav.x & 0xffff0000u);
    float a2 = __uint_as_float(eav.y << 16);
    float a3 = __uint_as_float(eav.y & 0xffff0000u);
    float a4 = __uint_as_float(eav.z << 16);
    float a5 = __uint_as_float(eav.z & 0xffff0000u);
    float a6 = __uint_as_float(eav.w << 16);
    float4 el = bd;
    el.x += a0*Wr[0].x; el.y += a0*Wr[0].y; el.z += a0*Wr[0].z; el.w += a0*Wr[0].w;
    el.x += a1*Wr[1].x; el.y += a1*Wr[1].y; el.z += a1*Wr[1].z; el.w += a1*Wr[1].w;
    el.x += a2*Wr[2].x; el.y += a2*Wr[2].y; el.z += a2*Wr[2].z; el.w += a2*Wr[2].w;
    el.x += a3*Wr[3].x; el.y += a3*Wr[3].y; el.z += a3*Wr[3].z; el.w += a3*Wr[3].w;
    el.x += a4*Wr[4].x; el.y += a4*Wr[4].y; el.z += a4*Wr[4].z; el.w += a4*Wr[4].w;
    el.x += a5*Wr[5].x; el.y += a5*Wr[5].y; el.z += a5*Wr[5].z; el.w += a5*Wr[5].w;
    el.x += a6*Wr[6].x; el.y += a6*Wr[6].y; el.z += a6*Wr[6].z; el.w += a6*Wr[6].w;
    acc.x += fmaxf(__uint_as_float(xv.x << 16)         + el.x, 0.f);
    acc.y += fmaxf(__uint_as_float(xv.x & 0xffff0000u) + el.y, 0.f);
    acc.z += fmaxf(__uint_as_float(xv.y << 16)         + el.z, 0.f);
    acc.w += fmaxf(__uint_as_float(xv.y & 0xffff0000u) + el.w, 0.f);
}

// GEMM tile: A (64x128 fp32) -> hi/lo bf16 in LDS; B frags prefetched from L2 per k-chunk.
__device__ __forceinline__ void gemm_tile(
    int r0, const float* __restrict__ in, float* __restrict__ out,
    const unsigned short* __restrict__ Wthi, const unsigned short* __restrict__ Wtlo,
    const float* __restrict__ b, const float* __restrict__ bng,
    const float* __restrict__ bnb, const float* __restrict__ bnm,
    const float* __restrict__ bnv, unsigned short* __restrict__ xb_out,
    unsigned short* A2) {
    int t = threadIdx.x;
    int w = t >> 6, lane = t & 63, q = lane >> 4, l16 = lane & 15;

    __syncthreads();   // A2 WAR safety across tiles/phases
    #pragma unroll
    for (int i = 0; i < 8; ++i) {
        int idx = t + i * 256;           // float4 index in 64x128 tile
        int row = idx >> 5;
        int kp = (idx & 31) * 4;
        float4 v = reinterpret_cast<const float4*>(in + (size_t)r0 * DIM)[idx];
        unsigned short h0 = f2bf(v.x), h1 = f2bf(v.y), h2 = f2bf(v.z), h3 = f2bf(v.w);
        ushort4 hv; hv.x = h0; hv.y = h1; hv.z = h2; hv.w = h3;
        ushort4 lv;
        lv.x = f2bf(v.x - bf2f(h0)); lv.y = f2bf(v.y - bf2f(h1));
        lv.z = f2bf(v.z - bf2f(h2)); lv.w = f2bf(v.w - bf2f(h3));
        *reinterpret_cast<ushort4*>(&A2[row * AST + kp]) = hv;
        *reinterpret_cast<ushort4*>(&A2[row * AST + 128 + kp]) = lv;
    }

    // B frags for kc=0 (issued while A-staging is in flight)
    bf16x8 cbh[2], cbl[2];
    #pragma unroll
    for (int nt = 0; nt < 2; ++nt) {
        int n = w * 32 + nt * 16 + l16;
        cbh[nt] = *reinterpret_cast<const bf16x8*>(Wthi + (size_t)n * DIM + q * 8);
        cbl[nt] = *reinterpret_cast<const bf16x8*>(Wtlo + (size_t)n * DIM + q * 8);
    }
    __syncthreads();

    f32x4 acc[4][2];
    #pragma unroll
    for (int mt = 0; mt < 4; ++mt)
        #pragma unroll
        for (int nt = 0; nt < 2; ++nt)
            acc[mt][nt] = (f32x4){0.f, 0.f, 0.f, 0.f};

    #pragma unroll
    for (int kc = 0; kc < 4; ++kc) {
        bf16x8 nbh[2], nbl[2];
        if (kc < 3) {
            #pragma unroll
            for (int nt = 0; nt < 2; ++nt) {
                int n = w * 32 + nt * 16 + l16;
                size_t o = (size_t)n * DIM + (kc + 1) * 32 + q * 8;
                nbh[nt] = *reinterpret_cast<const bf16x8*>(Wthi + o);
                nbl[nt] = *reinterpret_cast<const bf16x8*>(Wtlo + o);
            }
        }
        bf16x8 ahi[4], alo[4];
        #pragma unroll
        for (int mt = 0; mt < 4; ++mt) {
            ahi[mt] = *reinterpret_cast<const bf16x8*>(&A2[(mt * 16 + l16) * AST + kc * 32 + q * 8]);
            alo[mt] = *reinterpret_cast<const bf16x8*>(&A2[(mt * 16 + l16) * AST + 128 + kc * 32 + q * 8]);
        }
        #pragma unroll
        for (int mt = 0; mt < 4; ++mt)
            #pragma unroll
            for (int nt = 0; nt < 2; ++nt) {
                acc[mt][nt] = __builtin_amdgcn_mfma_f32_16x16x32_bf16(ahi[mt], cbh[nt], acc[mt][nt], 0, 0, 0);
                acc[mt][nt] = __builtin_amdgcn_mfma_f32_16x16x32_bf16(ahi[mt], cbl[nt], acc[mt][nt], 0, 0, 0);
                acc[mt][nt] = __builtin_amdgcn_mfma_f32_16x16x32_bf16(alo[mt], cbh[nt], acc[mt][nt], 0, 0, 0);
            }
        if (kc < 3) {
            #pragma unroll
            for (int nt = 0; nt < 2; ++nt) { cbh[nt] = nbh[nt]; cbl[nt] = nbl[nt]; }
        }
    }

    // epilogue: bias + BN + ReLU; C/D layout col=lane&15, row=quad*4+reg
    #pragma unroll
    for (int nt = 0; nt < 2; ++nt) {
        int col = w * 32 + nt * 16 + l16;
        float bias = b[col];
        float sc = bng[col] * rsqrtf(bnv[col] + BN_EPS);
        float sh = bnb[col] - bnm[col] * sc;
        #pragma unroll
        for (int mt = 0; mt < 4; ++mt) {
            #pragma unroll
            for (int r = 0; r < 4; ++r) {
                int row = r0 + mt * 16 + q * 4 + r;
                float o = fmaxf((acc[mt][nt][r] + bias) * sc + sh, 0.f);
                out[(size_t)row * DIM + col] = o;
                if (xb_out) xb_out[(size_t)row * DIM + col] = f2bf(o);
            }
        }
    }
}

__global__ __launch_bounds__(256, 3) void fused_gnn(FParams p) {
    __shared__ __align__(16) unsigned short A2[TM * AST];   // 33792 B; float scratch in pool phase
    __shared__ int s_ph[2];
    int t = threadIdx.x;
    int blk = blockIdx.x;
    int nblk = gridDim.x;
    int ph = 0;

    for (int l = 0; l < LAYERS; ++l) {
        // ---- aggregate: 8 nodes/group, 32 lanes/node, 4 feats/lane; 2-edge unroll ----
        {
            const float* eW = p.edge_W + (size_t)l * EDIM * DIM;
            const float* ebp = p.edge_b + (size_t)l * DIM;
            int nl = t >> 5, lane = t & 31, c0 = lane * 4;
            float4 Wr[EDIM];
            #pragma unroll
            for (int k = 0; k < EDIM; ++k)
                Wr[k] = *reinterpret_cast<const float4*>(eW + k * DIM + c0);
            float4 bd = *reinterpret_cast<const float4*>(ebp + c0);

            for (int grp = blk; grp < NGRP; grp += nblk) {
                int n = grp * 8 + nl;
                float4 acc = *reinterpret_cast<const float4*>(p.x + (size_t)n * DIM + c0);
                int idx = p.row_off[n], end = p.row_off[n + 1];
                for (; idx + 2 <= end; idx += 2) {
                    int e0 = p.csr[idx], e1 = p.csr[idx + 1];
                    int s0 = p.src[e0], s1 = p.src[e1];
                    uint4 ea0 = *reinterpret_cast<const uint4*>(p.ea8 + (size_t)e0 * 8);
                    uint4 ea1 = *reinterpret_cast<const uint4*>(p.ea8 + (size_t)e1 * 8);
                    uint2 x0 = *reinterpret_cast<const uint2*>(p.xb + (size_t)s0 * DIM + c0);
                    uint2 x1 = *reinterpret_cast<const uint2*>(p.xb + (size_t)s1 * DIM + c0);
                    edge_accum(acc, ea0, x0, Wr, bd);
                    edge_accum(acc, ea1, x1, Wr, bd);
                }
                if (idx < end) {
                    int e0 = p.csr[idx];
                    int s0 = p.src[e0];
                    uint4 ea0 = *reinterpret_cast<const uint4*>(p.ea8 + (size_t)e0 * 8);
                    uint2 x0 = *reinterpret_cast<const uint2*>(p.xb + (size_t)s0 * DIM + c0);
                    edge_accum(acc, ea0, x0, Wr, bd);
                }
                *reinterpret_cast<float4*>(p.h + (size_t)n * DIM + c0) = acc;
            }
        }
        gbar(p.bar, nblk * ++ph);

        // ---- GEMM1: h = relu(bn1(h @ W1 + b1)) (in-place) ----
        for (int tile = blk; tile < NTILES; tile += nblk)
            gemm_tile(tile * TM, p.h, p.h,
                      p.Wthi + ((size_t)l << 14), p.Wtlo + ((size_t)l << 14),
                      p.mlp_b1 + (size_t)l * DIM,
                      p.bn1_g + (size_t)l * DIM, p.bn1_b + (size_t)l * DIM,
                      p.bn1_m + (size_t)l * DIM, p.bn1_v + (size_t)l * DIM,
                      nullptr, A2);
        gbar(p.bar, nblk * ++ph);

        // ---- GEMM2: x = relu(bn2(h @ W2 + b2)), refresh xb ----
        for (int tile = blk; tile < NTILES; tile += nblk)
            gemm_tile(tile * TM, p.h, p.x,
                      p.Wthi + ((size_t)(LAYERS + l) << 14), p.Wtlo + ((size_t)(LAYERS + l) << 14),
                      p.mlp_b2 + (size_t)l * DIM,
                      p.bn2_g + (size_t)l * DIM, p.bn2_b + (size_t)l * DIM,
                      p.bn2_m + (size_t)l * DIM, p.bn2_v + (size_t)l * DIM,
                      p.xb, A2);
        gbar(p.bar, nblk * ++ph);
    }

    // ---- pool + head, one graph per block-pass ----
    float* sh = reinterpret_cast<float*>(A2);
    for (int gid = blk; gid < N_GRAPHS; gid += nblk) {
        __syncthreads();   // sh WAR safety
        if (t == 0) {
            int lo = 0, hi = N_NODES;
            while (lo < hi) { int mid = (lo + hi) >> 1; if (p.batch[mid] < gid) lo = mid + 1; else hi = mid; }
            s_ph[0] = lo;
        }
        if (t == 1) {
            int lo = 0, hi = N_NODES;
            while (lo < hi) { int mid = (lo + hi) >> 1; if (p.batch[mid] < gid + 1) lo = mid + 1; else hi = mid; }
            s_ph[1] = lo;
        }
        __syncthreads();
        int lo = s_ph[0], hi = s_ph[1];
        int d = t & 127, half = t >> 7;
        float a = 0.f;
        for (int n = lo + half; n < hi; n += 2) a += p.x[(size_t)n * DIM + d];
        sh[t] = a;
        __syncthreads();
        if (t < DIM) {
            float cnt = fmaxf((float)(hi - lo), 1.f);
            sh[512 + t] = (sh[t] + sh[t + 128]) / cnt;
        }
        __syncthreads();
        if (t < DIM) {
            float accv = p.head_b1[t];
            for (int k = 0; k < DIM; ++k) accv += sh[512 + k] * p.head_W1[k * DIM + t];
            sh[768 + t] = fmaxf(accv, 0.f);
        }
        __syncthreads();
        if (t < NCLASS) {
            float accv = p.head_b2[t];
            for (int k = 0; k < DIM; ++k) accv += sh[768 + k] * p.head_W2[k * NCLASS + t];
            p.out[gid * NCLASS + t] = accv;
        }
        __syncthreads();
    }
}

// ---------------- launch ----------------

extern "C" void kernel_launch(void* const* d_in, const int* in_sizes, int n_in,
                              void* d_out, int out_size, void* d_ws, size_t ws_size,
                              hipStream_t stream) {
    const float* edge_attr = (const float*)d_in[0];
    const int*   edge_index = (const int*)d_in[1];
    const int*   batch = (const int*)d_in[2];
    const float* node_emb = (const float*)d_in[3];
    const float* edge_W = (const float*)d_in[4];
    const float* edge_b = (const float*)d_in[5];
    const float* mlp_W1 = (const float*)d_in[6];
    const float* mlp_b1 = (const float*)d_in[7];
    const float* bn1_g = (const float*)d_in[8];
    const float* bn1_b = (const float*)d_in[9];
    const float* bn1_m = (const float*)d_in[10];
    const float* bn1_v = (const float*)d_in[11];
    const float* mlp_W2 = (const float*)d_in[12];
    const float* mlp_b2 = (const float*)d_in[13];
    const float* bn2_g = (const float*)d_in[14];
    const float* bn2_b = (const float*)d_in[15];
    const float* bn2_m = (const float*)d_in[16];
    const float* bn2_v = (const float*)d_in[17];
    const float* head_W1 = (const float*)d_in[18];
    const float* head_b1 = (const float*)d_in[19];
    const float* head_W2 = (const float*)d_in[20];
    const float* head_b2 = (const float*)d_in[21];
    float* out = (float*)d_out;

    const int* src = edge_index;
    const int* dst = edge_index + N_EDGES;

    size_t off = 0;
    auto carve = [&](size_t bytes) {
        void* p = (char*)d_ws + off;
        off += (bytes + 255) & ~(size_t)255;
        return p;
    };
    float* x            = (float*)carve((size_t)N_PAD * DIM * 4);
    unsigned short* xb  = (unsigned short*)carve((size_t)N_PAD * DIM * 2);
    float* h            = (float*)carve((size_t)N_PAD * DIM * 4);
    unsigned short* ea8 = (unsigned short*)carve((size_t)N_EDGES * 8 * 2);
    unsigned short* Wthi = (unsigned short*)carve((size_t)2 * LAYERS * DIM * DIM * 2);
    unsigned short* Wtlo = (unsigned short*)carve((size_t)2 * LAYERS * DIM * DIM * 2);
    int* deg      = (int*)carve((size_t)N_NODES * 4);
    int* row_off  = (int*)carve((size_t)(N_NODES + 1) * 4);
    int* csr      = (int*)carve((size_t)N_EDGES * 4);
    int* bar      = (int*)carve(256);
    (void)ws_size;

    zero_ints<<<(N_NODES + 255) / 256, 256, 0, stream>>>(deg, N_NODES);
    hist_kernel<<<(N_EDGES + 255) / 256, 256, 0, stream>>>(dst, deg);
    scan_kernel<<<1, 1024, 0, stream>>>(deg, row_off);
    zero_ints<<<(N_NODES + 255) / 256, 256, 0, stream>>>(deg, N_NODES);
    fill_csr<<<(N_EDGES + 255) / 256, 256, 0, stream>>>(dst, row_off, deg, csr);

    init_x<<<(N_NODES * DIM + 255) / 256, 256, 0, stream>>>(x, xb, node_emb);
    prep_ea<<<(N_EDGES * 8 + 255) / 256, 256, 0, stream>>>(edge_attr, ea8);
    prep_w<<<(2 * LAYERS * DIM * DIM + 255) / 256, 256, 0, stream>>>(mlp_W1, mlp_W2, Wthi, Wtlo);
    zero_ints<<<1, 256, 0, stream>>>(bar, 64);

    FParams p;
    p.batch = batch;
    p.edge_W = edge_W; p.edge_b = edge_b;
    p.mlp_b1 = mlp_b1; p.bn1_g = bn1_g; p.bn1_b = bn1_b; p.bn1_m = bn1_m; p.bn1_v = bn1_v;
    p.mlp_b2 = mlp_b2; p.bn2_g = bn2_g; p.bn2_b = bn2_b; p.bn2_m = bn2_m; p.bn2_v = bn2_v;
    p.head_W1 = head_W1; p.head_b1 = head_b1; p.head_W2 = head_W2; p.head_b2 = head_b2;
    p.x = x; p.xb = xb; p.h = h;
    p.ea8 = ea8; p.Wthi = Wthi; p.Wtlo = Wtlo;
    p.src = src; p.csr = csr; p.row_off = row_off;
    p.bar = bar;
    p.out = out;

    // Size grid by MEASURED occupancy so the spin barrier can never deadlock.
    int blocksPerCU = 0;
    hipError_t oe = hipOccupancyMaxActiveBlocksPerMultiprocessor(&blocksPerCU, fused_gnn, 256, 0);
    if (oe != hipSuccess || blocksPerCU < 1) blocksPerCU = 1;
    int nblk = blocksPerCU * 256;
    if (nblk > 1024) nblk = 1024;

    fused_gnn<<<nblk, 256, 0, stream>>>(p);
}

// Round 7
// 786.385 us; speedup vs baseline: 3.2710x; 3.2710x over previous
//
#include <hip/hip_runtime.h>

#define N_NODES 50000
#define N_PAD   50048   // multiple of 64; pad rows garbage, never consumed
#define N_EDGES 800000
#define N_GRAPHS 500
#define DIM 128
#define EDIM 7
#define LAYERS 5
#define NCLASS 10
#define BN_EPS 1e-5f
#define TM 64
#define AST 264         // LDS A row stride (ushort): 528 B = odd 16B multiple -> conflict-free b128
#define NSB ((N_NODES + 256) / 256)   // 196 scan blocks

typedef __attribute__((ext_vector_type(8))) short bf16x8;
typedef __attribute__((ext_vector_type(4))) float f32x4;

__device__ __forceinline__ unsigned short f2bf(float f) {
    unsigned u = __float_as_uint(f);
    u = u + 0x7fffu + ((u >> 16) & 1u);   // RNE
    return (unsigned short)(u >> 16);
}
__device__ __forceinline__ float bf2f(unsigned short h) {
    return __uint_as_float(((unsigned)h) << 16);
}

// ---------------- CSR build ----------------

__global__ void zero_ints(int* __restrict__ p, int n) {
    int i = blockIdx.x * 256 + threadIdx.x;
    if (i < n) p[i] = 0;
}

__global__ void hist_kernel(const int* __restrict__ dst, int* __restrict__ deg) {
    int e = blockIdx.x * 256 + threadIdx.x;
    if (e < N_EDGES) atomicAdd(&deg[dst[e]], 1);
}

// multi-block scan, phase 1: block-local exclusive scan + block sums
__global__ __launch_bounds__(256)
void scan1(const int* __restrict__ deg, int* __restrict__ ro, int* __restrict__ bsums) {
    __shared__ int ws[4];
    int t = threadIdx.x;
    int i = blockIdx.x * 256 + t;
    int v = (i < N_NODES) ? deg[i] : 0;
    int lane = t & 63, wv = t >> 6;
    int s = v;
    #pragma unroll
    for (int off = 1; off < 64; off <<= 1) {
        int u = __shfl_up(s, off, 64);
        if (lane >= off) s += u;
    }
    if (lane == 63) ws[wv] = s;
    __syncthreads();
    if (t == 0) {
        int a = 0;
        #pragma unroll
        for (int k = 0; k < 4; ++k) { int x = ws[k]; ws[k] = a; a += x; }
        bsums[blockIdx.x] = a;
    }
    __syncthreads();
    int excl = s - v + ws[wv];
    if (i <= N_NODES) ro[i] = excl;
}

// phase 2: exclusive scan of NSB (<=256) block sums, single block
__global__ __launch_bounds__(256)
void scan2(int* __restrict__ bsums) {
    __shared__ int ws[4];
    int t = threadIdx.x;
    int v = (t < NSB) ? bsums[t] : 0;
    int lane = t & 63, wv = t >> 6;
    int s = v;
    #pragma unroll
    for (int off = 1; off < 64; off <<= 1) {
        int u = __shfl_up(s, off, 64);
        if (lane >= off) s += u;
    }
    if (lane == 63) ws[wv] = s;
    __syncthreads();
    if (t == 0) {
        int a = 0;
        #pragma unroll
        for (int k = 0; k < 4; ++k) { int x = ws[k]; ws[k] = a; a += x; }
    }
    __syncthreads();
    if (t < NSB) bsums[t] = s - v + ws[wv];
}

// phase 3: add block offsets; also materialize cursor copy for fill_csr
__global__ __launch_bounds__(256)
void scan3(int* __restrict__ ro, const int* __restrict__ bsums, int* __restrict__ cursor) {
    int i = blockIdx.x * 256 + threadIdx.x;
    if (i <= N_NODES) {
        int r = ro[i] + bsums[i >> 8];
        ro[i] = r;
        if (i < N_NODES) cursor[i] = r;
    }
}

__global__ void fill_csr(const int* __restrict__ dst, int* __restrict__ cursor,
                         int* __restrict__ csr_edges) {
    int e = blockIdx.x * 256 + threadIdx.x;
    if (e < N_EDGES) {
        int pos = atomicAdd(&cursor[dst[e]], 1);   // absolute position
        csr_edges[pos] = e;
    }
}

// ---------------- one-time preps ----------------

__global__ void init_x(float* __restrict__ x, unsigned short* __restrict__ xb,
                       const float* __restrict__ emb) {
    int i = blockIdx.x * 256 + threadIdx.x;
    if (i < N_NODES * DIM) {
        float v = emb[i & (DIM - 1)];
        x[i] = v;
        xb[i] = f2bf(v);
    }
}

__global__ void prep_ea(const float* __restrict__ ea, unsigned short* __restrict__ ea8) {
    int i = blockIdx.x * 256 + threadIdx.x;
    if (i < N_EDGES * 8) {
        int e = i >> 3, k = i & 7;
        float v = (k < EDIM) ? ea[e * EDIM + k] : 0.f;
        ea8[i] = f2bf(v);
    }
}

// W [k][n] fp32 -> transposed hi/lo bf16 Wt[m][n][k]
__global__ void prep_w(const float* __restrict__ W1, const float* __restrict__ W2,
                       unsigned short* __restrict__ Wthi, unsigned short* __restrict__ Wtlo) {
    int i = blockIdx.x * 256 + threadIdx.x;
    if (i >= 2 * LAYERS * DIM * DIM) return;
    int m = i >> 14;
    int n = i & 127;
    int k = (i >> 7) & 127;
    const float* W = (m < LAYERS) ? (W1 + (size_t)m * DIM * DIM)
                                  : (W2 + (size_t)(m - LAYERS) * DIM * DIM);
    float v = W[k * DIM + n];
    unsigned short hi = f2bf(v);
    float lo = v - bf2f(hi);
    size_t o = ((size_t)m << 14) + (size_t)n * DIM + k;
    Wthi[o] = hi;
    Wtlo[o] = f2bf(lo);
}

// ---------------- aggregation ----------------
// 8 nodes/256-block, 32 lanes/node, 4 feats/lane. W pinned in registers via asm
// (prevents the rematerialization seen in R3/R4: VGPR_Count 36/60 vs ~90 needed).
// 4-edge chunks with next-chunk index prefetch for memory-level parallelism.

__device__ __forceinline__ void edge_accum(float4& acc, uint4 eav, uint2 xv,
                                           const float4* Wr, const float4& bd) {
    float a0 = __uint_as_float(eav.x << 16);
    float a1 = __uint_as_float(eav.x & 0xffff0000u);
    float a2 = __uint_as_float(eav.y << 16);
    float a3 = __uint_as_float(eav.y & 0xffff0000u);
    float a4 = __uint_as_float(eav.z << 16);
    float a5 = __uint_as_float(eav.z & 0xffff0000u);
    float a6 = __uint_as_float(eav.w << 16);
    float4 el = bd;
    el.x += a0*Wr[0].x; el.y += a0*Wr[0].y; el.z += a0*Wr[0].z; el.w += a0*Wr[0].w;
    el.x += a1*Wr[1].x; el.y += a1*Wr[1].y; el.z += a1*Wr[1].z; el.w += a1*Wr[1].w;
    el.x += a2*Wr[2].x; el.y += a2*Wr[2].y; el.z += a2*Wr[2].z; el.w += a2*Wr[2].w;
    el.x += a3*Wr[3].x; el.y += a3*Wr[3].y; el.z += a3*Wr[3].z; el.w += a3*Wr[3].w;
    el.x += a4*Wr[4].x; el.y += a4*Wr[4].y; el.z += a4*Wr[4].z; el.w += a4*Wr[4].w;
    el.x += a5*Wr[5].x; el.y += a5*Wr[5].y; el.z += a5*Wr[5].z; el.w += a5*Wr[5].w;
    el.x += a6*Wr[6].x; el.y += a6*Wr[6].y; el.z += a6*Wr[6].z; el.w += a6*Wr[6].w;
    acc.x += fmaxf(__uint_as_float(xv.x << 16)         + el.x, 0.f);
    acc.y += fmaxf(__uint_as_float(xv.x & 0xffff0000u) + el.y, 0.f);
    acc.z += fmaxf(__uint_as_float(xv.y << 16)         + el.z, 0.f);
    acc.w += fmaxf(__uint_as_float(xv.y & 0xffff0000u) + el.w, 0.f);
}

__global__ __launch_bounds__(256, 4)
void aggregate(const float* __restrict__ x, const unsigned short* __restrict__ xb,
               float* __restrict__ h,
               const unsigned short* __restrict__ ea8,
               const int* __restrict__ srcA,
               const int* __restrict__ csr,
               const int* __restrict__ row_off,
               const float* __restrict__ eW, const float* __restrict__ eb) {
    int t = threadIdx.x;
    int nl = t >> 5, lane = t & 31, c0 = lane * 4;
    int n = blockIdx.x * 8 + nl;

    float4 Wr[EDIM];
    #pragma unroll
    for (int k = 0; k < EDIM; ++k)
        Wr[k] = *reinterpret_cast<const float4*>(eW + k * DIM + c0);
    float4 bd = *reinterpret_cast<const float4*>(eb + c0);
    // pin: outputs of opaque asm cannot be rematerialized as re-loads
    #pragma unroll
    for (int k = 0; k < EDIM; ++k)
        asm volatile("" : "+v"(Wr[k].x), "+v"(Wr[k].y), "+v"(Wr[k].z), "+v"(Wr[k].w));
    asm volatile("" : "+v"(bd.x), "+v"(bd.y), "+v"(bd.z), "+v"(bd.w));

    float4 acc = *reinterpret_cast<const float4*>(x + (size_t)n * DIM + c0);
    int idx = row_off[n], end = row_off[n + 1];

    int e_c[4], s_c[4];
    bool have = (idx + 4 <= end);
    if (have) {
        #pragma unroll
        for (int j = 0; j < 4; ++j) e_c[j] = csr[idx + j];
        #pragma unroll
        for (int j = 0; j < 4; ++j) s_c[j] = srcA[e_c[j]];
    }
    while (have) {
        uint4 ea[4]; uint2 xv[4];
        #pragma unroll
        for (int j = 0; j < 4; ++j) ea[j] = *reinterpret_cast<const uint4*>(ea8 + (size_t)e_c[j] * 8);
        #pragma unroll
        for (int j = 0; j < 4; ++j) xv[j] = *reinterpret_cast<const uint2*>(xb + (size_t)s_c[j] * DIM + c0);
        idx += 4;
        bool nxt = (idx + 4 <= end);
        int e_n[4], s_n[4];
        if (nxt) {
            #pragma unroll
            for (int j = 0; j < 4; ++j) e_n[j] = csr[idx + j];
            #pragma unroll
            for (int j = 0; j < 4; ++j) s_n[j] = srcA[e_n[j]];
        }
        #pragma unroll
        for (int j = 0; j < 4; ++j) edge_accum(acc, ea[j], xv[j], Wr, bd);
        if (nxt) {
            #pragma unroll
            for (int j = 0; j < 4; ++j) { e_c[j] = e_n[j]; s_c[j] = s_n[j]; }
        }
        have = nxt;
    }
    for (; idx < end; ++idx) {
        int e = csr[idx];
        int s = srcA[e];
        uint4 ea = *reinterpret_cast<const uint4*>(ea8 + (size_t)e * 8);
        uint2 xv = *reinterpret_cast<const uint2*>(xb + (size_t)s * DIM + c0);
        edge_accum(acc, ea, xv, Wr, bd);
    }
    *reinterpret_cast<float4*>(h + (size_t)n * DIM + c0) = acc;
}

// ---------------- MFMA GEMM (hi/lo bf16 split) + bias + BN + ReLU ----------------
// B fragments in registers (loaded at entry, in flight during A staging); A staged
// once in LDS with hi/lo split; ONE barrier; K-loop pure LDS+MFMA.

__global__ __launch_bounds__(256)
void gemm_mfma(const float* __restrict__ in, float* __restrict__ out,
               const unsigned short* __restrict__ Wthi,
               const unsigned short* __restrict__ Wtlo,
               const float* __restrict__ b,
               const float* __restrict__ bng, const float* __restrict__ bnb,
               const float* __restrict__ bnm, const float* __restrict__ bnv,
               unsigned short* __restrict__ xb_out) {
    __shared__ __align__(16) unsigned short A2[TM * AST];   // 33792 B
    int t = threadIdx.x;
    int r0 = blockIdx.x * TM;
    int w = t >> 6;
    int lane = t & 63;
    int q = lane >> 4;
    int l16 = lane & 15;

    // B register fragments: n = w*32 + nt*16 + l16, k-contiguous rows of Wt
    bf16x8 bhi[2][4], blo[2][4];
    #pragma unroll
    for (int nt = 0; nt < 2; ++nt) {
        int n = w * 32 + nt * 16 + l16;
        const bf16x8* gh = reinterpret_cast<const bf16x8*>(Wthi + (size_t)n * DIM);
        const bf16x8* gl = reinterpret_cast<const bf16x8*>(Wtlo + (size_t)n * DIM);
        #pragma unroll
        for (int kc = 0; kc < 4; ++kc) {
            bhi[nt][kc] = gh[kc * 4 + q];
            blo[nt][kc] = gl[kc * 4 + q];
        }
    }

    // stage A with hi/lo split (coalesced float4 reads)
    #pragma unroll
    for (int i = 0; i < 8; ++i) {
        int idx = t + i * 256;
        int row = idx >> 5;
        int kp = (idx & 31) * 4;
        float4 v = reinterpret_cast<const float4*>(in + (size_t)r0 * DIM)[idx];
        unsigned short h0 = f2bf(v.x), h1 = f2bf(v.y), h2 = f2bf(v.z), h3 = f2bf(v.w);
        ushort4 hv; hv.x = h0; hv.y = h1; hv.z = h2; hv.w = h3;
        ushort4 lv;
        lv.x = f2bf(v.x - bf2f(h0)); lv.y = f2bf(v.y - bf2f(h1));
        lv.z = f2bf(v.z - bf2f(h2)); lv.w = f2bf(v.w - bf2f(h3));
        *reinterpret_cast<ushort4*>(&A2[row * AST + kp]) = hv;
        *reinterpret_cast<ushort4*>(&A2[row * AST + 128 + kp]) = lv;
    }
    __syncthreads();   // the only barrier

    f32x4 acc[4][2];
    #pragma unroll
    for (int mt = 0; mt < 4; ++mt)
        #pragma unroll
        for (int nt = 0; nt < 2; ++nt)
            acc[mt][nt] = (f32x4){0.f, 0.f, 0.f, 0.f};

    #pragma unroll
    for (int kc = 0; kc < 4; ++kc) {
        bf16x8 ahi[4], alo[4];
        #pragma unroll
        for (int mt = 0; mt < 4; ++mt) {
            ahi[mt] = *reinterpret_cast<const bf16x8*>(&A2[(mt * 16 + l16) * AST + kc * 32 + q * 8]);
            alo[mt] = *reinterpret_cast<const bf16x8*>(&A2[(mt * 16 + l16) * AST + 128 + kc * 32 + q * 8]);
        }
        #pragma unroll
        for (int mt = 0; mt < 4; ++mt)
            #pragma unroll
            for (int nt = 0; nt < 2; ++nt) {
                acc[mt][nt] = __builtin_amdgcn_mfma_f32_16x16x32_bf16(ahi[mt], bhi[nt][kc], acc[mt][nt], 0, 0, 0);
                acc[mt][nt] = __builtin_amdgcn_mfma_f32_16x16x32_bf16(ahi[mt], blo[nt][kc], acc[mt][nt], 0, 0, 0);
                acc[mt][nt] = __builtin_amdgcn_mfma_f32_16x16x32_bf16(alo[mt], bhi[nt][kc], acc[mt][nt], 0, 0, 0);
            }
    }

    // epilogue: bias + BN + ReLU; C/D layout col=lane&15, row=quad*4+reg
    #pragma unroll
    for (int nt = 0; nt < 2; ++nt) {
        int col = w * 32 + nt * 16 + l16;
        float bias = b[col];
        float sc = bng[col] * rsqrtf(bnv[col] + BN_EPS);
        float sh = bnb[col] - bnm[col] * sc;
        #pragma unroll
        for (int mt = 0; mt < 4; ++mt) {
            #pragma unroll
            for (int r = 0; r < 4; ++r) {
                int row = r0 + mt * 16 + q * 4 + r;
                float o = fmaxf((acc[mt][nt][r] + bias) * sc + sh, 0.f);
                out[(size_t)row * DIM + col] = o;
                if (xb_out) xb_out[(size_t)row * DIM + col] = f2bf(o);
            }
        }
    }
}

// ---------------- global mean pool (batch sorted), 2 rows in flight ----------------

__global__ __launch_bounds__(256)
void pool_kernel(const float* __restrict__ x, const int* __restrict__ batch,
                 float* __restrict__ g) {
    __shared__ float sh[256];
    __shared__ int sb[2];
    int gid = blockIdx.x;
    int t = threadIdx.x;
    if (t < 2) {
        int tgt = gid + t;
        int lo = 0, hi = N_NODES;
        while (lo < hi) { int mid = (lo + hi) >> 1; if (batch[mid] < tgt) lo = mid + 1; else hi = mid; }
        sb[t] = lo;
    }
    __syncthreads();
    int lo = sb[0], hi = sb[1];
    int d = t & 127, half = t >> 7;
    float a = 0.f;
    for (int n = lo + half; n < hi; n += 2) a += x[(size_t)n * DIM + d];
    sh[t] = a;
    __syncthreads();
    if (t < DIM) {
        float cnt = fmaxf((float)(hi - lo), 1.f);
        g[gid * DIM + t] = (sh[t] + sh[t + 128]) / cnt;
    }
}

// ---------------- head ----------------

__global__ __launch_bounds__(128)
void head1_kernel(const float* __restrict__ g, const float* __restrict__ W1,
                  const float* __restrict__ b1, float* __restrict__ h1) {
    __shared__ float gs[DIM];
    int gid = blockIdx.x, c = threadIdx.x;
    gs[c] = g[gid * DIM + c];
    __syncthreads();
    float acc = b1[c];
    for (int k = 0; k < DIM; ++k) acc += gs[k] * W1[k * DIM + c];
    h1[gid * DIM + c] = fmaxf(acc, 0.f);
}

__global__ __launch_bounds__(64)
void head2_kernel(const float* __restrict__ h1, const float* __restrict__ W2,
                  const float* __restrict__ b2, float* __restrict__ out) {
    __shared__ float hs[DIM];
    int gid = blockIdx.x;
    int t = threadIdx.x;
    hs[t] = h1[gid * DIM + t];
    hs[t + 64] = h1[gid * DIM + t + 64];
    __syncthreads();
    if (t < NCLASS) {
        float acc = b2[t];
        for (int k = 0; k < DIM; ++k) acc += hs[k] * W2[k * NCLASS + t];
        out[gid * NCLASS + t] = acc;
    }
}

// ---------------- launch ----------------

extern "C" void kernel_launch(void* const* d_in, const int* in_sizes, int n_in,
                              void* d_out, int out_size, void* d_ws, size_t ws_size,
                              hipStream_t stream) {
    const float* edge_attr = (const float*)d_in[0];
    const int*   edge_index = (const int*)d_in[1];
    const int*   batch = (const int*)d_in[2];
    const float* node_emb = (const float*)d_in[3];
    const float* edge_W = (const float*)d_in[4];
    const float* edge_b = (const float*)d_in[5];
    const float* mlp_W1 = (const float*)d_in[6];
    const float* mlp_b1 = (const float*)d_in[7];
    const float* bn1_g = (const float*)d_in[8];
    const float* bn1_b = (const float*)d_in[9];
    const float* bn1_m = (const float*)d_in[10];
    const float* bn1_v = (const float*)d_in[11];
    const float* mlp_W2 = (const float*)d_in[12];
    const float* mlp_b2 = (const float*)d_in[13];
    const float* bn2_g = (const float*)d_in[14];
    const float* bn2_b = (const float*)d_in[15];
    const float* bn2_m = (const float*)d_in[16];
    const float* bn2_v = (const float*)d_in[17];
    const float* head_W1 = (const float*)d_in[18];
    const float* head_b1 = (const float*)d_in[19];
    const float* head_W2 = (const float*)d_in[20];
    const float* head_b2 = (const float*)d_in[21];
    float* out = (float*)d_out;

    const int* src = edge_index;
    const int* dst = edge_index + N_EDGES;

    size_t off = 0;
    auto carve = [&](size_t bytes) {
        void* p = (char*)d_ws + off;
        off += (bytes + 255) & ~(size_t)255;
        return p;
    };
    float* x            = (float*)carve((size_t)N_PAD * DIM * 4);
    unsigned short* xb  = (unsigned short*)carve((size_t)N_PAD * DIM * 2);
    float* h            = (float*)carve((size_t)N_PAD * DIM * 4);
    unsigned short* ea8 = (unsigned short*)carve((size_t)N_EDGES * 8 * 2);
    unsigned short* Wthi = (unsigned short*)carve((size_t)2 * LAYERS * DIM * DIM * 2);
    unsigned short* Wtlo = (unsigned short*)carve((size_t)2 * LAYERS * DIM * DIM * 2);
    int* deg      = (int*)carve((size_t)N_NODES * 4);
    int* row_off  = (int*)carve((size_t)(N_NODES + 1) * 4);
    int* cursor   = (int*)carve((size_t)N_NODES * 4);
    int* csr      = (int*)carve((size_t)N_EDGES * 4);
    int* bsums    = (int*)carve((size_t)NSB * 4);
    float* gbuf   = (float*)carve((size_t)N_GRAPHS * DIM * 4);
    float* h1buf  = (float*)carve((size_t)N_GRAPHS * DIM * 4);
    (void)ws_size;

    // CSR build
    zero_ints<<<(N_NODES + 255) / 256, 256, 0, stream>>>(deg, N_NODES);
    hist_kernel<<<(N_EDGES + 255) / 256, 256, 0, stream>>>(dst, deg);
    scan1<<<NSB, 256, 0, stream>>>(deg, row_off, bsums);
    scan2<<<1, 256, 0, stream>>>(bsums);
    scan3<<<NSB, 256, 0, stream>>>(row_off, bsums, cursor);
    fill_csr<<<(N_EDGES + 255) / 256, 256, 0, stream>>>(dst, cursor, csr);

    init_x<<<(N_NODES * DIM + 255) / 256, 256, 0, stream>>>(x, xb, node_emb);
    prep_ea<<<(N_EDGES * 8 + 255) / 256, 256, 0, stream>>>(edge_attr, ea8);
    prep_w<<<(2 * LAYERS * DIM * DIM + 255) / 256, 256, 0, stream>>>(mlp_W1, mlp_W2, Wthi, Wtlo);

    const int gemm_blocks = N_PAD / TM;   // 782
    for (int l = 0; l < LAYERS; ++l) {
        aggregate<<<N_NODES / 8, 256, 0, stream>>>(
            x, xb, h, ea8, src, csr, row_off,
            edge_W + (size_t)l * EDIM * DIM, edge_b + (size_t)l * DIM);
        gemm_mfma<<<gemm_blocks, 256, 0, stream>>>(
            h, h,
            Wthi + ((size_t)l << 14), Wtlo + ((size_t)l << 14),
            mlp_b1 + (size_t)l * DIM,
            bn1_g + (size_t)l * DIM, bn1_b + (size_t)l * DIM,
            bn1_m + (size_t)l * DIM, bn1_v + (size_t)l * DIM,
            nullptr);
        gemm_mfma<<<gemm_blocks, 256, 0, stream>>>(
            h, x,
            Wthi + ((size_t)(LAYERS + l) << 14), Wtlo + ((size_t)(LAYERS + l) << 14),
            mlp_b2 + (size_t)l * DIM,
            bn2_g + (size_t)l * DIM, bn2_b + (size_t)l * DIM,
            bn2_m + (size_t)l * DIM, bn2_v + (size_t)l * DIM,
            xb);
    }

    pool_kernel<<<N_GRAPHS, 256, 0, stream>>>(x, batch, gbuf);
    head1_kernel<<<N_GRAPHS, 128, 0, stream>>>(gbuf, head_W1, head_b1, h1buf);
    head2_kernel<<<N_GRAPHS, 64, 0, stream>>>(h1buf, head_W2, head_b2, out);
}

// Round 10
// 712.627 us; speedup vs baseline: 3.6095x; 1.1035x over previous
//
#include <hip/hip_runtime.h>

#define N_NODES 50000
#define N_PAD   50048   // multiple of 64; pad rows garbage, never consumed
#define N_EDGES 800000
#define N_GRAPHS 500
#define DIM 128
#define EDIM 7
#define LAYERS 5
#define NCLASS 10
#define BN_EPS 1e-5f
#define TM 64
#define AST 264         // LDS A row stride (ushort): 528 B = odd 16B multiple -> conflict-free b128
#define NSB ((N_NODES + 256) / 256)   // 196 scan blocks

typedef __attribute__((ext_vector_type(8))) short bf16x8;
typedef __attribute__((ext_vector_type(4))) float f32x4;
typedef _Float16 h2 __attribute__((ext_vector_type(2)));

__device__ __forceinline__ unsigned short f2bf(float f) {
    unsigned u = __float_as_uint(f);
    u = u + 0x7fffu + ((u >> 16) & 1u);   // RNE
    return (unsigned short)(u >> 16);
}
__device__ __forceinline__ float bf2f(unsigned short h) {
    return __uint_as_float(((unsigned)h) << 16);
}
__device__ __forceinline__ h2 u2h2(unsigned u) {
    union { unsigned u; h2 h; } c; c.u = u; return c.h;
}
__device__ __forceinline__ unsigned h22u(h2 h) {
    union { h2 h; unsigned u; } c; c.h = h; return c.u;
}
__device__ __forceinline__ unsigned packh2(float a, float b) {
    h2 h; h.x = (_Float16)a; h.y = (_Float16)b;   // RNE casts
    return h22u(h);
}

// ---------------- CSR build ----------------

__global__ void zero_ints(int* __restrict__ p, int n) {
    int i = blockIdx.x * 256 + threadIdx.x;
    if (i < n) p[i] = 0;
}

__global__ void hist_kernel(const int* __restrict__ dst, int* __restrict__ deg) {
    int e = blockIdx.x * 256 + threadIdx.x;
    if (e < N_EDGES) atomicAdd(&deg[dst[e]], 1);
}

__global__ __launch_bounds__(256)
void scan1(const int* __restrict__ deg, int* __restrict__ ro, int* __restrict__ bsums) {
    __shared__ int ws[4];
    int t = threadIdx.x;
    int i = blockIdx.x * 256 + t;
    int v = (i < N_NODES) ? deg[i] : 0;
    int lane = t & 63, wv = t >> 6;
    int s = v;
    #pragma unroll
    for (int off = 1; off < 64; off <<= 1) {
        int u = __shfl_up(s, off, 64);
        if (lane >= off) s += u;
    }
    if (lane == 63) ws[wv] = s;
    __syncthreads();
    if (t == 0) {
        int a = 0;
        #pragma unroll
        for (int k = 0; k < 4; ++k) { int x = ws[k]; ws[k] = a; a += x; }
        bsums[blockIdx.x] = a;
    }
    __syncthreads();
    int excl = s - v + ws[wv];
    if (i <= N_NODES) ro[i] = excl;
}

__global__ __launch_bounds__(256)
void scan2(int* __restrict__ bsums) {
    __shared__ int ws[4];
    int t = threadIdx.x;
    int v = (t < NSB) ? bsums[t] : 0;
    int lane = t & 63, wv = t >> 6;
    int s = v;
    #pragma unroll
    for (int off = 1; off < 64; off <<= 1) {
        int u = __shfl_up(s, off, 64);
        if (lane >= off) s += u;
    }
    if (lane == 63) ws[wv] = s;
    __syncthreads();
    if (t == 0) {
        int a = 0;
        #pragma unroll
        for (int k = 0; k < 4; ++k) { int x = ws[k]; ws[k] = a; a += x; }
    }
    __syncthreads();
    if (t < NSB) bsums[t] = s - v + ws[wv];
}

__global__ __launch_bounds__(256)
void scan3(int* __restrict__ ro, const int* __restrict__ bsums, int* __restrict__ cursor) {
    int i = blockIdx.x * 256 + threadIdx.x;
    if (i <= N_NODES) {
        int r = ro[i] + bsums[i >> 8];
        ro[i] = r;
        if (i < N_NODES) cursor[i] = r;
    }
}

__global__ void fill_csr(const int* __restrict__ dst, int* __restrict__ cursor,
                         int* __restrict__ csr_edges) {
    int e = blockIdx.x * 256 + threadIdx.x;
    if (e < N_EDGES) {
        int pos = atomicAdd(&cursor[dst[e]], 1);
        csr_edges[pos] = e;
    }
}

// ---------------- one-time preps ----------------

__global__ void init_x(float* __restrict__ x, unsigned short* __restrict__ xb,
                       const float* __restrict__ emb) {
    int i = blockIdx.x * 256 + threadIdx.x;
    if (i < N_NODES * DIM) {
        float v = emb[i & (DIM - 1)];
        x[i] = v;
        xb[i] = f2bf(v);
    }
}

// edge_attr [E,7] fp32 -> fp16 padded [E,8]
__global__ void prep_ea(const float* __restrict__ ea, _Float16* __restrict__ eah) {
    int i = blockIdx.x * 256 + threadIdx.x;
    if (i < N_EDGES * 8) {
        int e = i >> 3, k = i & 7;
        float v = (k < EDIM) ? ea[e * EDIM + k] : 0.f;
        eah[i] = (_Float16)v;
    }
}

// W [k][n] fp32 -> transposed hi/lo bf16 Wt[m][n][k]
__global__ void prep_w(const float* __restrict__ W1, const float* __restrict__ W2,
                       unsigned short* __restrict__ Wthi, unsigned short* __restrict__ Wtlo) {
    int i = blockIdx.x * 256 + threadIdx.x;
    if (i >= 2 * LAYERS * DIM * DIM) return;
    int m = i >> 14;
    int n = i & 127;
    int k = (i >> 7) & 127;
    const float* W = (m < LAYERS) ? (W1 + (size_t)m * DIM * DIM)
                                  : (W2 + (size_t)(m - LAYERS) * DIM * DIM);
    float v = W[k * DIM + n];
    unsigned short hi = f2bf(v);
    float lo = v - bf2f(hi);
    size_t o = ((size_t)m << 14) + (size_t)n * DIM + k;
    Wthi[o] = hi;
    Wtlo[o] = f2bf(lo);
}

// ---------------- aggregation ----------------
// 8 nodes/256-block, 32 lanes/node, 4 feats/lane. Edge linear via v_dot2_f32_f16:
// ea held packed (uint4 = 8 fp16), W packed to 16 half2 regs -> 16 fdot2 per edge.

#if __has_builtin(__builtin_amdgcn_fdot2)
#define HAVE_FDOT2 1
#else
#define HAVE_FDOT2 0
#endif

__device__ __forceinline__ void edge_accum(float4& acc, uint4 eav, uint2 xv,
                                           const unsigned* Wp, const float4& bd) {
    float4 el = bd;
#if HAVE_FDOT2
    #pragma unroll
    for (int d = 0; d < 4; ++d) {
        float e = (d == 0) ? el.x : (d == 1) ? el.y : (d == 2) ? el.z : el.w;
        e = __builtin_amdgcn_fdot2(u2h2(eav.x), u2h2(Wp[d * 4 + 0]), e, false);
        e = __builtin_amdgcn_fdot2(u2h2(eav.y), u2h2(Wp[d * 4 + 1]), e, false);
        e = __builtin_amdgcn_fdot2(u2h2(eav.z), u2h2(Wp[d * 4 + 2]), e, false);
        e = __builtin_amdgcn_fdot2(u2h2(eav.w), u2h2(Wp[d * 4 + 3]), e, false);
        if (d == 0) el.x = e; else if (d == 1) el.y = e; else if (d == 2) el.z = e; else el.w = e;
    }
#else
    h2 ea01 = u2h2(eav.x), ea23 = u2h2(eav.y), ea45 = u2h2(eav.z), ea67 = u2h2(eav.w);
    float a[8] = {(float)ea01.x, (float)ea01.y, (float)ea23.x, (float)ea23.y,
                  (float)ea45.x, (float)ea45.y, (float)ea67.x, 0.f};
    #pragma unroll
    for (int d = 0; d < 4; ++d) {
        float e = (d == 0) ? el.x : (d == 1) ? el.y : (d == 2) ? el.z : el.w;
        #pragma unroll
        for (int kp = 0; kp < 4; ++kp) {
            h2 w = u2h2(Wp[d * 4 + kp]);
            e += a[kp * 2] * (float)w.x + a[kp * 2 + 1] * (float)w.y;
        }
        if (d == 0) el.x = e; else if (d == 1) el.y = e; else if (d == 2) el.z = e; else el.w = e;
    }
#endif
    acc.x += fmaxf(__uint_as_float(xv.x << 16)         + el.x, 0.f);
    acc.y += fmaxf(__uint_as_float(xv.x & 0xffff0000u) + el.y, 0.f);
    acc.z += fmaxf(__uint_as_float(xv.y << 16)         + el.z, 0.f);
    acc.w += fmaxf(__uint_as_float(xv.y & 0xffff0000u) + el.w, 0.f);
}

__global__ __launch_bounds__(256, 4)
void aggregate(const float* __restrict__ x, const unsigned short* __restrict__ xb,
               float* __restrict__ h,
               const _Float16* __restrict__ eah,
               const int* __restrict__ srcA,
               const int* __restrict__ csr,
               const int* __restrict__ row_off,
               const float* __restrict__ eW, const float* __restrict__ eb) {
    int t = threadIdx.x;
    int nl = t >> 5, lane = t & 31, c0 = lane * 4;
    int n = blockIdx.x * 8 + nl;

    // pack W[k][c0+d] (k=0..6, pad k=7 with 0) into 16 half2: Wp[d*4+kp] = (W[2kp][d], W[2kp+1][d])
    unsigned Wp[16];
    #pragma unroll
    for (int d = 0; d < 4; ++d) {
        #pragma unroll
        for (int kp = 0; kp < 4; ++kp) {
            float w0 = eW[(kp * 2) * DIM + c0 + d];
            float w1 = (kp * 2 + 1 < EDIM) ? eW[(kp * 2 + 1) * DIM + c0 + d] : 0.f;
            Wp[d * 4 + kp] = packh2(w0, w1);
        }
    }
    float4 bd = *reinterpret_cast<const float4*>(eb + c0);
    #pragma unroll
    for (int k = 0; k < 16; ++k) asm volatile("" : "+v"(Wp[k]));
    asm volatile("" : "+v"(bd.x), "+v"(bd.y), "+v"(bd.z), "+v"(bd.w));

    float4 acc = *reinterpret_cast<const float4*>(x + (size_t)n * DIM + c0);
    int idx = row_off[n], end = row_off[n + 1];

    int e_c[4], s_c[4];
    bool have = (idx + 4 <= end);
    if (have) {
        #pragma unroll
        for (int j = 0; j < 4; ++j) e_c[j] = csr[idx + j];
        #pragma unroll
        for (int j = 0; j < 4; ++j) s_c[j] = srcA[e_c[j]];
    }
    while (have) {
        uint4 ea[4]; uint2 xv[4];
        #pragma unroll
        for (int j = 0; j < 4; ++j) ea[j] = *reinterpret_cast<const uint4*>(eah + (size_t)e_c[j] * 8);
        #pragma unroll
        for (int j = 0; j < 4; ++j) xv[j] = *reinterpret_cast<const uint2*>(xb + (size_t)s_c[j] * DIM + c0);
        idx += 4;
        bool nxt = (idx + 4 <= end);
        int e_n[4], s_n[4];
        if (nxt) {
            #pragma unroll
            for (int j = 0; j < 4; ++j) e_n[j] = csr[idx + j];
            #pragma unroll
            for (int j = 0; j < 4; ++j) s_n[j] = srcA[e_n[j]];
        }
        #pragma unroll
        for (int j = 0; j < 4; ++j) edge_accum(acc, ea[j], xv[j], Wp, bd);
        if (nxt) {
            #pragma unroll
            for (int j = 0; j < 4; ++j) { e_c[j] = e_n[j]; s_c[j] = s_n[j]; }
        }
        have = nxt;
    }
    for (; idx < end; ++idx) {
        int e = csr[idx];
        int s = srcA[e];
        uint4 ea = *reinterpret_cast<const uint4*>(eah + (size_t)e * 8);
        uint2 xv = *reinterpret_cast<const uint2*>(xb + (size_t)s * DIM + c0);
        edge_accum(acc, ea, xv, Wp, bd);
    }
    *reinterpret_cast<float4*>(h + (size_t)n * DIM + c0) = acc;
}

// ---------------- fused double MFMA GEMM: x = bn2relu( bn1relu(h@W1+b1) @ W2 + b2 ) ----------------
// A staged once; intermediate round-trips through the SAME LDS tile (hi/lo bf16);
// B fragments in registers; hi/lo split keeps fp32-class accuracy.

__global__ __launch_bounds__(256)
void gemm2x(const float* __restrict__ in, float* __restrict__ outx,
            unsigned short* __restrict__ xb_out,
            const unsigned short* __restrict__ W1hi, const unsigned short* __restrict__ W1lo,
            const unsigned short* __restrict__ W2hi, const unsigned short* __restrict__ W2lo,
            const float* __restrict__ b1,
            const float* __restrict__ bn1g, const float* __restrict__ bn1b,
            const float* __restrict__ bn1m, const float* __restrict__ bn1v,
            const float* __restrict__ b2,
            const float* __restrict__ bn2g, const float* __restrict__ bn2b,
            const float* __restrict__ bn2m, const float* __restrict__ bn2v) {
    __shared__ __align__(16) unsigned short A2[TM * AST];   // 33792 B
    int t = threadIdx.x;
    int r0 = blockIdx.x * TM;
    int w = t >> 6;
    int lane = t & 63;
    int q = lane >> 4;
    int l16 = lane & 15;

    // B1 register fragments (in flight during A staging)
    bf16x8 bh[2][4], bl[2][4];
    #pragma unroll
    for (int nt = 0; nt < 2; ++nt) {
        int n = w * 32 + nt * 16 + l16;
        const bf16x8* gh = reinterpret_cast<const bf16x8*>(W1hi + (size_t)n * DIM);
        const bf16x8* gl = reinterpret_cast<const bf16x8*>(W1lo + (size_t)n * DIM);
        #pragma unroll
        for (int kc = 0; kc < 4; ++kc) {
            bh[nt][kc] = gh[kc * 4 + q];
            bl[nt][kc] = gl[kc * 4 + q];
        }
    }

    // stage A (hi/lo split)
    #pragma unroll
    for (int i = 0; i < 8; ++i) {
        int idx = t + i * 256;
        int row = idx >> 5;
        int kp = (idx & 31) * 4;
        float4 v = reinterpret_cast<const float4*>(in + (size_t)r0 * DIM)[idx];
        unsigned short h0 = f2bf(v.x), h1 = f2bf(v.y), h2_ = f2bf(v.z), h3 = f2bf(v.w);
        ushort4 hv; hv.x = h0; hv.y = h1; hv.z = h2_; hv.w = h3;
        ushort4 lv;
        lv.x = f2bf(v.x - bf2f(h0)); lv.y = f2bf(v.y - bf2f(h1));
        lv.z = f2bf(v.z - bf2f(h2_)); lv.w = f2bf(v.w - bf2f(h3));
        *reinterpret_cast<ushort4*>(&A2[row * AST + kp]) = hv;
        *reinterpret_cast<ushort4*>(&A2[row * AST + 128 + kp]) = lv;
    }
    __syncthreads();

    f32x4 acc[4][2];
    #pragma unroll
    for (int mt = 0; mt < 4; ++mt)
        #pragma unroll
        for (int nt = 0; nt < 2; ++nt)
            acc[mt][nt] = (f32x4){0.f, 0.f, 0.f, 0.f};

    #pragma unroll
    for (int kc = 0; kc < 4; ++kc) {
        bf16x8 ahi[4], alo[4];
        #pragma unroll
        for (int mt = 0; mt < 4; ++mt) {
            ahi[mt] = *reinterpret_cast<const bf16x8*>(&A2[(mt * 16 + l16) * AST + kc * 32 + q * 8]);
            alo[mt] = *reinterpret_cast<const bf16x8*>(&A2[(mt * 16 + l16) * AST + 128 + kc * 32 + q * 8]);
        }
        #pragma unroll
        for (int mt = 0; mt < 4; ++mt)
            #pragma unroll
            for (int nt = 0; nt < 2; ++nt) {
                acc[mt][nt] = __builtin_amdgcn_mfma_f32_16x16x32_bf16(ahi[mt], bh[nt][kc], acc[mt][nt], 0, 0, 0);
                acc[mt][nt] = __builtin_amdgcn_mfma_f32_16x16x32_bf16(ahi[mt], bl[nt][kc], acc[mt][nt], 0, 0, 0);
                acc[mt][nt] = __builtin_amdgcn_mfma_f32_16x16x32_bf16(alo[mt], bh[nt][kc], acc[mt][nt], 0, 0, 0);
            }
    }
    __syncthreads();   // all Kloop1 reads done before A2 overwrite

    // epilogue 1: bias + BN1 + ReLU -> back into A2 (hi/lo), local rows
    #pragma unroll
    for (int nt = 0; nt < 2; ++nt) {
        int col = w * 32 + nt * 16 + l16;
        float bias = b1[col];
        float sc = bn1g[col] * rsqrtf(bn1v[col] + BN_EPS);
        float sh = bn1b[col] - bn1m[col] * sc;
        #pragma unroll
        for (int mt = 0; mt < 4; ++mt) {
            #pragma unroll
            for (int r = 0; r < 4; ++r) {
                int rowl = mt * 16 + q * 4 + r;
                float o = fmaxf((acc[mt][nt][r] + bias) * sc + sh, 0.f);
                unsigned short hi = f2bf(o);
                A2[rowl * AST + col] = hi;
                A2[rowl * AST + 128 + col] = f2bf(o - bf2f(hi));
            }
        }
    }

    // B2 fragments (loads overlap the LDS writes above)
    #pragma unroll
    for (int nt = 0; nt < 2; ++nt) {
        int n = w * 32 + nt * 16 + l16;
        const bf16x8* gh = reinterpret_cast<const bf16x8*>(W2hi + (size_t)n * DIM);
        const bf16x8* gl = reinterpret_cast<const bf16x8*>(W2lo + (size_t)n * DIM);
        #pragma unroll
        for (int kc = 0; kc < 4; ++kc) {
            bh[nt][kc] = gh[kc * 4 + q];
            bl[nt][kc] = gl[kc * 4 + q];
        }
    }
    __syncthreads();

    #pragma unroll
    for (int mt = 0; mt < 4; ++mt)
        #pragma unroll
        for (int nt = 0; nt < 2; ++nt)
            acc[mt][nt] = (f32x4){0.f, 0.f, 0.f, 0.f};

    #pragma unroll
    for (int kc = 0; kc < 4; ++kc) {
        bf16x8 ahi[4], alo[4];
        #pragma unroll
        for (int mt = 0; mt < 4; ++mt) {
            ahi[mt] = *reinterpret_cast<const bf16x8*>(&A2[(mt * 16 + l16) * AST + kc * 32 + q * 8]);
            alo[mt] = *reinterpret_cast<const bf16x8*>(&A2[(mt * 16 + l16) * AST + 128 + kc * 32 + q * 8]);
        }
        #pragma unroll
        for (int mt = 0; mt < 4; ++mt)
            #pragma unroll
            for (int nt = 0; nt < 2; ++nt) {
                acc[mt][nt] = __builtin_amdgcn_mfma_f32_16x16x32_bf16(ahi[mt], bh[nt][kc], acc[mt][nt], 0, 0, 0);
                acc[mt][nt] = __builtin_amdgcn_mfma_f32_16x16x32_bf16(ahi[mt], bl[nt][kc], acc[mt][nt], 0, 0, 0);
                acc[mt][nt] = __builtin_amdgcn_mfma_f32_16x16x32_bf16(alo[mt], bh[nt][kc], acc[mt][nt], 0, 0, 0);
            }
    }

    // epilogue 2: bias + BN2 + ReLU -> x + xb
    #pragma unroll
    for (int nt = 0; nt < 2; ++nt) {
        int col = w * 32 + nt * 16 + l16;
        float bias = b2[col];
        float sc = bn2g[col] * rsqrtf(bn2v[col] + BN_EPS);
        float sh = bn2b[col] - bn2m[col] * sc;
        #pragma unroll
        for (int mt = 0; mt < 4; ++mt) {
            #pragma unroll
            for (int r = 0; r < 4; ++r) {
                int row = r0 + mt * 16 + q * 4 + r;
                float o = fmaxf((acc[mt][nt][r] + bias) * sc + sh, 0.f);
                outx[(size_t)row * DIM + col] = o;
                xb_out[(size_t)row * DIM + col] = f2bf(o);
            }
        }
    }
}

// ---------------- global mean pool (batch sorted) ----------------

__global__ __launch_bounds__(256)
void pool_kernel(const float* __restrict__ x, const int* __restrict__ batch,
                 float* __restrict__ g) {
    __shared__ float sh[256];
    __shared__ int sb[2];
    int gid = blockIdx.x;
    int t = threadIdx.x;
    if (t < 2) {
        int tgt = gid + t;
        int lo = 0, hi = N_NODES;
        while (lo < hi) { int mid = (lo + hi) >> 1; if (batch[mid] < tgt) lo = mid + 1; else hi = mid; }
        sb[t] = lo;
    }
    __syncthreads();
    int lo = sb[0], hi = sb[1];
    int d = t & 127, half = t >> 7;
    float a = 0.f;
    for (int n = lo + half; n < hi; n += 2) a += x[(size_t)n * DIM + d];
    sh[t] = a;
    __syncthreads();
    if (t < DIM) {
        float cnt = fmaxf((float)(hi - lo), 1.f);
        g[gid * DIM + t] = (sh[t] + sh[t + 128]) / cnt;
    }
}

// ---------------- head ----------------

__global__ __launch_bounds__(128)
void head1_kernel(const float* __restrict__ g, const float* __restrict__ W1,
                  const float* __restrict__ b1, float* __restrict__ h1) {
    __shared__ float gs[DIM];
    int gid = blockIdx.x, c = threadIdx.x;
    gs[c] = g[gid * DIM + c];
    __syncthreads();
    float acc = b1[c];
    for (int k = 0; k < DIM; ++k) acc += gs[k] * W1[k * DIM + c];
    h1[gid * DIM + c] = fmaxf(acc, 0.f);
}

__global__ __launch_bounds__(64)
void head2_kernel(const float* __restrict__ h1, const float* __restrict__ W2,
                  const float* __restrict__ b2, float* __restrict__ out) {
    __shared__ float hs[DIM];
    int gid = blockIdx.x;
    int t = threadIdx.x;
    hs[t] = h1[gid * DIM + t];
    hs[t + 64] = h1[gid * DIM + t + 64];
    __syncthreads();
    if (t < NCLASS) {
        float acc = b2[t];
        for (int k = 0; k < DIM; ++k) acc += hs[k] * W2[k * NCLASS + t];
        out[gid * NCLASS + t] = acc;
    }
}

// ---------------- launch ----------------

extern "C" void kernel_launch(void* const* d_in, const int* in_sizes, int n_in,
                              void* d_out, int out_size, void* d_ws, size_t ws_size,
                              hipStream_t stream) {
    const float* edge_attr = (const float*)d_in[0];
    const int*   edge_index = (const int*)d_in[1];
    const int*   batch = (const int*)d_in[2];
    const float* node_emb = (const float*)d_in[3];
    const float* edge_W = (const float*)d_in[4];
    const float* edge_b = (const float*)d_in[5];
    const float* mlp_W1 = (const float*)d_in[6];
    const float* mlp_b1 = (const float*)d_in[7];
    const float* bn1_g = (const float*)d_in[8];
    const float* bn1_b = (const float*)d_in[9];
    const float* bn1_m = (const float*)d_in[10];
    const float* bn1_v = (const float*)d_in[11];
    const float* mlp_W2 = (const float*)d_in[12];
    const float* mlp_b2 = (const float*)d_in[13];
    const float* bn2_g = (const float*)d_in[14];
    const float* bn2_b = (const float*)d_in[15];
    const float* bn2_m = (const float*)d_in[16];
    const float* bn2_v = (const float*)d_in[17];
    const float* head_W1 = (const float*)d_in[18];
    const float* head_b1 = (const float*)d_in[19];
    const float* head_W2 = (const float*)d_in[20];
    const float* head_b2 = (const float*)d_in[21];
    float* out = (float*)d_out;

    const int* src = edge_index;
    const int* dst = edge_index + N_EDGES;

    size_t off = 0;
    auto carve = [&](size_t bytes) {
        void* p = (char*)d_ws + off;
        off += (bytes + 255) & ~(size_t)255;
        return p;
    };
    float* x            = (float*)carve((size_t)N_PAD * DIM * 4);
    unsigned short* xb  = (unsigned short*)carve((size_t)N_PAD * DIM * 2);
    float* h            = (float*)carve((size_t)N_PAD * DIM * 4);
    _Float16* eah       = (_Float16*)carve((size_t)N_EDGES * 8 * 2);
    unsigned short* Wthi = (unsigned short*)carve((size_t)2 * LAYERS * DIM * DIM * 2);
    unsigned short* Wtlo = (unsigned short*)carve((size_t)2 * LAYERS * DIM * DIM * 2);
    int* deg      = (int*)carve((size_t)N_NODES * 4);
    int* row_off  = (int*)carve((size_t)(N_NODES + 1) * 4);
    int* cursor   = (int*)carve((size_t)N_NODES * 4);
    int* csr      = (int*)carve((size_t)N_EDGES * 4);
    int* bsums    = (int*)carve((size_t)NSB * 4);
    float* gbuf   = (float*)carve((size_t)N_GRAPHS * DIM * 4);
    float* h1buf  = (float*)carve((size_t)N_GRAPHS * DIM * 4);
    (void)ws_size;

    // CSR build
    zero_ints<<<(N_NODES + 255) / 256, 256, 0, stream>>>(deg, N_NODES);
    hist_kernel<<<(N_EDGES + 255) / 256, 256, 0, stream>>>(dst, deg);
    scan1<<<NSB, 256, 0, stream>>>(deg, row_off, bsums);
    scan2<<<1, 256, 0, stream>>>(bsums);
    scan3<<<NSB, 256, 0, stream>>>(row_off, bsums, cursor);
    fill_csr<<<(N_EDGES + 255) / 256, 256, 0, stream>>>(dst, cursor, csr);

    init_x<<<(N_NODES * DIM + 255) / 256, 256, 0, stream>>>(x, xb, node_emb);
    prep_ea<<<(N_EDGES * 8 + 255) / 256, 256, 0, stream>>>(edge_attr, eah);
    prep_w<<<(2 * LAYERS * DIM * DIM + 255) / 256, 256, 0, stream>>>(mlp_W1, mlp_W2, Wthi, Wtlo);

    const int gemm_blocks = N_PAD / TM;   // 782
    for (int l = 0; l < LAYERS; ++l) {
        aggregate<<<N_NODES / 8, 256, 0, stream>>>(
            x, xb, h, eah, src, csr, row_off,
            edge_W + (size_t)l * EDIM * DIM, edge_b + (size_t)l * DIM);
        gemm2x<<<gemm_blocks, 256, 0, stream>>>(
            h, x, xb,
            Wthi + ((size_t)l << 14), Wtlo + ((size_t)l << 14),
            Wthi + ((size_t)(LAYERS + l) << 14), Wtlo + ((size_t)(LAYERS + l) << 14),
            mlp_b1 + (size_t)l * DIM,
            bn1_g + (size_t)l * DIM, bn1_b + (size_t)l * DIM,
            bn1_m + (size_t)l * DIM, bn1_v + (size_t)l * DIM,
            mlp_b2 + (size_t)l * DIM,
            bn2_g + (size_t)l * DIM, bn2_b + (size_t)l * DIM,
            bn2_m + (size_t)l * DIM, bn2_v + (size_t)l * DIM);
    }

    pool_kernel<<<N_GRAPHS, 256, 0, stream>>>(x, batch, gbuf);
    head1_kernel<<<N_GRAPHS, 128, 0, stream>>>(gbuf, head_W1, head_b1, h1buf);
    head2_kernel<<<N_GRAPHS, 64, 0, stream>>>(h1buf, head_W2, head_b2, out);
}

// Round 11
// 652.631 us; speedup vs baseline: 3.9413x; 1.0919x over previous
//
#include <hip/hip_runtime.h>

#define N_NODES 50000
#define N_PAD   50048   // multiple of 64; pad rows garbage, never consumed
#define N_EDGES 800000
#define N_GRAPHS 500
#define DIM 128
#define EDIM 7
#define LAYERS 5
#define NCLASS 10
#define BN_EPS 1e-5f
#define TM 64
#define AST 264         // LDS A row stride (ushort): 528 B = odd 16B multiple -> conflict-free b128
#define NSB ((N_NODES + 256) / 256)   // 196 scan blocks

typedef __attribute__((ext_vector_type(8))) short bf16x8;
typedef __attribute__((ext_vector_type(4))) float f32x4;
typedef _Float16 h2 __attribute__((ext_vector_type(2)));

__device__ __forceinline__ unsigned short f2bf(float f) {
    unsigned u = __float_as_uint(f);
    u = u + 0x7fffu + ((u >> 16) & 1u);   // RNE
    return (unsigned short)(u >> 16);
}
__device__ __forceinline__ float bf2f(unsigned short h) {
    return __uint_as_float(((unsigned)h) << 16);
}
__device__ __forceinline__ h2 u2h2(unsigned u) {
    union { unsigned u; h2 h; } c; c.u = u; return c.h;
}
__device__ __forceinline__ unsigned h22u(h2 h) {
    union { h2 h; unsigned u; } c; c.h = h; return c.u;
}
__device__ __forceinline__ unsigned packh2(float a, float b) {
    h2 h; h.x = (_Float16)a; h.y = (_Float16)b;   // RNE casts
    return h22u(h);
}

// ---------------- CSR build ----------------

__global__ void zero_ints(int* __restrict__ p, int n) {
    int i = blockIdx.x * 256 + threadIdx.x;
    if (i < n) p[i] = 0;
}

__global__ void hist_kernel(const int* __restrict__ dst, int* __restrict__ deg) {
    int e = blockIdx.x * 256 + threadIdx.x;
    if (e < N_EDGES) atomicAdd(&deg[dst[e]], 1);
}

__global__ __launch_bounds__(256)
void scan1(const int* __restrict__ deg, int* __restrict__ ro, int* __restrict__ bsums) {
    __shared__ int ws[4];
    int t = threadIdx.x;
    int i = blockIdx.x * 256 + t;
    int v = (i < N_NODES) ? deg[i] : 0;
    int lane = t & 63, wv = t >> 6;
    int s = v;
    #pragma unroll
    for (int off = 1; off < 64; off <<= 1) {
        int u = __shfl_up(s, off, 64);
        if (lane >= off) s += u;
    }
    if (lane == 63) ws[wv] = s;
    __syncthreads();
    if (t == 0) {
        int a = 0;
        #pragma unroll
        for (int k = 0; k < 4; ++k) { int x = ws[k]; ws[k] = a; a += x; }
        bsums[blockIdx.x] = a;
    }
    __syncthreads();
    int excl = s - v + ws[wv];
    if (i <= N_NODES) ro[i] = excl;
}

__global__ __launch_bounds__(256)
void scan2(int* __restrict__ bsums) {
    __shared__ int ws[4];
    int t = threadIdx.x;
    int v = (t < NSB) ? bsums[t] : 0;
    int lane = t & 63, wv = t >> 6;
    int s = v;
    #pragma unroll
    for (int off = 1; off < 64; off <<= 1) {
        int u = __shfl_up(s, off, 64);
        if (lane >= off) s += u;
    }
    if (lane == 63) ws[wv] = s;
    __syncthreads();
    if (t == 0) {
        int a = 0;
        #pragma unroll
        for (int k = 0; k < 4; ++k) { int x = ws[k]; ws[k] = a; a += x; }
    }
    __syncthreads();
    if (t < NSB) bsums[t] = s - v + ws[wv];
}

__global__ __launch_bounds__(256)
void scan3(int* __restrict__ ro, const int* __restrict__ bsums, int* __restrict__ cursor) {
    int i = blockIdx.x * 256 + threadIdx.x;
    if (i <= N_NODES) {
        int r = ro[i] + bsums[i >> 8];
        ro[i] = r;
        if (i < N_NODES) cursor[i] = r;
    }
}

__global__ void fill_csr(const int* __restrict__ dst, int* __restrict__ cursor,
                         int* __restrict__ csr_edges) {
    int e = blockIdx.x * 256 + threadIdx.x;
    if (e < N_EDGES) {
        int pos = atomicAdd(&cursor[dst[e]], 1);
        csr_edges[pos] = e;
    }
}

// ---------------- one-time preps ----------------

__global__ void init_x(float* __restrict__ x, unsigned short* __restrict__ xb,
                       const float* __restrict__ emb) {
    int i = blockIdx.x * 256 + threadIdx.x;
    if (i < N_NODES * DIM) {
        float v = emb[i & (DIM - 1)];
        x[i] = v;
        xb[i] = f2bf(v);
    }
}

// edge_attr [E,7] fp32 -> fp16 padded [E,8] (original edge order)
__global__ void prep_ea(const float* __restrict__ ea, _Float16* __restrict__ eah) {
    int i = blockIdx.x * 256 + threadIdx.x;
    if (i < N_EDGES * 8) {
        int e = i >> 3, k = i & 7;
        float v = (k < EDIM) ? ea[e * EDIM + k] : 0.f;
        eah[i] = (_Float16)v;
    }
}

// permute src + edge_attr into CSR order: kills the csr->src chain and makes
// the per-layer ea read fully sequential (was 51 MB random-line fetch/layer)
__global__ void prep_perm(const int* __restrict__ csr, const int* __restrict__ src,
                          const _Float16* __restrict__ eah,
                          int* __restrict__ srcc, _Float16* __restrict__ eac) {
    int i = blockIdx.x * 256 + threadIdx.x;
    if (i < N_EDGES) {
        int e = csr[i];
        srcc[i] = src[e];
        *reinterpret_cast<uint4*>(eac + (size_t)i * 8) =
            *reinterpret_cast<const uint4*>(eah + (size_t)e * 8);
    }
}

// W [k][n] fp32 -> transposed hi/lo bf16 Wt[m][n][k]
__global__ void prep_w(const float* __restrict__ W1, const float* __restrict__ W2,
                       unsigned short* __restrict__ Wthi, unsigned short* __restrict__ Wtlo) {
    int i = blockIdx.x * 256 + threadIdx.x;
    if (i >= 2 * LAYERS * DIM * DIM) return;
    int m = i >> 14;
    int n = i & 127;
    int k = (i >> 7) & 127;
    const float* W = (m < LAYERS) ? (W1 + (size_t)m * DIM * DIM)
                                  : (W2 + (size_t)(m - LAYERS) * DIM * DIM);
    float v = W[k * DIM + n];
    unsigned short hi = f2bf(v);
    float lo = v - bf2f(hi);
    size_t o = ((size_t)m << 14) + (size_t)n * DIM + k;
    Wthi[o] = hi;
    Wtlo[o] = f2bf(lo);
}

// ---------------- aggregation ----------------
// 8 nodes/256-block, 32 lanes/node, 4 feats/lane. Edge linear via v_dot2_f32_f16.
// srcc/eac are CSR-ordered -> sequential reads; only xb gather is random.

#if __has_builtin(__builtin_amdgcn_fdot2)
#define HAVE_FDOT2 1
#else
#define HAVE_FDOT2 0
#endif

__device__ __forceinline__ void edge_accum(float4& acc, uint4 eav, uint2 xv,
                                           const unsigned* Wp, const float4& bd) {
    float4 el = bd;
#if HAVE_FDOT2
    #pragma unroll
    for (int d = 0; d < 4; ++d) {
        float e = (d == 0) ? el.x : (d == 1) ? el.y : (d == 2) ? el.z : el.w;
        e = __builtin_amdgcn_fdot2(u2h2(eav.x), u2h2(Wp[d * 4 + 0]), e, false);
        e = __builtin_amdgcn_fdot2(u2h2(eav.y), u2h2(Wp[d * 4 + 1]), e, false);
        e = __builtin_amdgcn_fdot2(u2h2(eav.z), u2h2(Wp[d * 4 + 2]), e, false);
        e = __builtin_amdgcn_fdot2(u2h2(eav.w), u2h2(Wp[d * 4 + 3]), e, false);
        if (d == 0) el.x = e; else if (d == 1) el.y = e; else if (d == 2) el.z = e; else el.w = e;
    }
#else
    h2 ea01 = u2h2(eav.x), ea23 = u2h2(eav.y), ea45 = u2h2(eav.z), ea67 = u2h2(eav.w);
    float a[8] = {(float)ea01.x, (float)ea01.y, (float)ea23.x, (float)ea23.y,
                  (float)ea45.x, (float)ea45.y, (float)ea67.x, 0.f};
    #pragma unroll
    for (int d = 0; d < 4; ++d) {
        float e = (d == 0) ? el.x : (d == 1) ? el.y : (d == 2) ? el.z : el.w;
        #pragma unroll
        for (int kp = 0; kp < 4; ++kp) {
            h2 w = u2h2(Wp[d * 4 + kp]);
            e += a[kp * 2] * (float)w.x + a[kp * 2 + 1] * (float)w.y;
        }
        if (d == 0) el.x = e; else if (d == 1) el.y = e; else if (d == 2) el.z = e; else el.w = e;
    }
#endif
    acc.x += fmaxf(__uint_as_float(xv.x << 16)         + el.x, 0.f);
    acc.y += fmaxf(__uint_as_float(xv.x & 0xffff0000u) + el.y, 0.f);
    acc.z += fmaxf(__uint_as_float(xv.y << 16)         + el.z, 0.f);
    acc.w += fmaxf(__uint_as_float(xv.y & 0xffff0000u) + el.w, 0.f);
}

__global__ __launch_bounds__(256, 6)   // 6 blocks/CU (24/32 waves) — was 4 (48% occ cap)
void aggregate(const float* __restrict__ x, const unsigned short* __restrict__ xb,
               float* __restrict__ h,
               const _Float16* __restrict__ eac,
               const int* __restrict__ srcc,
               const int* __restrict__ row_off,
               const float* __restrict__ eW, const float* __restrict__ eb) {
    int t = threadIdx.x;
    int nl = t >> 5, lane = t & 31, c0 = lane * 4;
    int n = blockIdx.x * 8 + nl;

    // pack W[k][c0+d] (k=0..6, pad k=7 with 0) into 16 half2: Wp[d*4+kp] = (W[2kp][d], W[2kp+1][d])
    unsigned Wp[16];
    #pragma unroll
    for (int d = 0; d < 4; ++d) {
        #pragma unroll
        for (int kp = 0; kp < 4; ++kp) {
            float w0 = eW[(kp * 2) * DIM + c0 + d];
            float w1 = (kp * 2 + 1 < EDIM) ? eW[(kp * 2 + 1) * DIM + c0 + d] : 0.f;
            Wp[d * 4 + kp] = packh2(w0, w1);
        }
    }
    float4 bd = *reinterpret_cast<const float4*>(eb + c0);
    #pragma unroll
    for (int k = 0; k < 16; ++k) asm volatile("" : "+v"(Wp[k]));
    asm volatile("" : "+v"(bd.x), "+v"(bd.y), "+v"(bd.z), "+v"(bd.w));

    float4 acc = *reinterpret_cast<const float4*>(x + (size_t)n * DIM + c0);
    int idx = row_off[n], end = row_off[n + 1];

    int s_c[4];
    bool have = (idx + 4 <= end);
    if (have) {
        #pragma unroll
        for (int j = 0; j < 4; ++j) s_c[j] = srcc[idx + j];
    }
    while (have) {
        uint4 ea[4]; uint2 xv[4];
        #pragma unroll
        for (int j = 0; j < 4; ++j) ea[j] = *reinterpret_cast<const uint4*>(eac + (size_t)(idx + j) * 8);
        #pragma unroll
        for (int j = 0; j < 4; ++j) xv[j] = *reinterpret_cast<const uint2*>(xb + (size_t)s_c[j] * DIM + c0);
        idx += 4;
        bool nxt = (idx + 4 <= end);
        int s_n[4];
        if (nxt) {
            #pragma unroll
            for (int j = 0; j < 4; ++j) s_n[j] = srcc[idx + j];
        }
        #pragma unroll
        for (int j = 0; j < 4; ++j) edge_accum(acc, ea[j], xv[j], Wp, bd);
        if (nxt) {
            #pragma unroll
            for (int j = 0; j < 4; ++j) s_c[j] = s_n[j];
        }
        have = nxt;
    }
    for (; idx < end; ++idx) {
        int s = srcc[idx];
        uint4 ea = *reinterpret_cast<const uint4*>(eac + (size_t)idx * 8);
        uint2 xv = *reinterpret_cast<const uint2*>(xb + (size_t)s * DIM + c0);
        edge_accum(acc, ea, xv, Wp, bd);
    }
    *reinterpret_cast<float4*>(h + (size_t)n * DIM + c0) = acc;
}

// ---------------- fused double MFMA GEMM: x = bn2relu( bn1relu(h@W1+b1) @ W2 + b2 ) ----------------
// A staged once; intermediate round-trips through the SAME LDS tile (hi/lo bf16);
// B fragments in registers; hi/lo split keeps fp32-class accuracy.

__global__ __launch_bounds__(256)
void gemm2x(const float* __restrict__ in, float* __restrict__ outx,
            unsigned short* __restrict__ xb_out,
            const unsigned short* __restrict__ W1hi, const unsigned short* __restrict__ W1lo,
            const unsigned short* __restrict__ W2hi, const unsigned short* __restrict__ W2lo,
            const float* __restrict__ b1,
            const float* __restrict__ bn1g, const float* __restrict__ bn1b,
            const float* __restrict__ bn1m, const float* __restrict__ bn1v,
            const float* __restrict__ b2,
            const float* __restrict__ bn2g, const float* __restrict__ bn2b,
            const float* __restrict__ bn2m, const float* __restrict__ bn2v) {
    __shared__ __align__(16) unsigned short A2[TM * AST];   // 33792 B
    int t = threadIdx.x;
    int r0 = blockIdx.x * TM;
    int w = t >> 6;
    int lane = t & 63;
    int q = lane >> 4;
    int l16 = lane & 15;

    // B1 register fragments (in flight during A staging)
    bf16x8 bh[2][4], bl[2][4];
    #pragma unroll
    for (int nt = 0; nt < 2; ++nt) {
        int n = w * 32 + nt * 16 + l16;
        const bf16x8* gh = reinterpret_cast<const bf16x8*>(W1hi + (size_t)n * DIM);
        const bf16x8* gl = reinterpret_cast<const bf16x8*>(W1lo + (size_t)n * DIM);
        #pragma unroll
        for (int kc = 0; kc < 4; ++kc) {
            bh[nt][kc] = gh[kc * 4 + q];
            bl[nt][kc] = gl[kc * 4 + q];
        }
    }

    // stage A (hi/lo split)
    #pragma unroll
    for (int i = 0; i < 8; ++i) {
        int idx = t + i * 256;
        int row = idx >> 5;
        int kp = (idx & 31) * 4;
        float4 v = reinterpret_cast<const float4*>(in + (size_t)r0 * DIM)[idx];
        unsigned short h0 = f2bf(v.x), h1 = f2bf(v.y), h2_ = f2bf(v.z), h3 = f2bf(v.w);
        ushort4 hv; hv.x = h0; hv.y = h1; hv.z = h2_; hv.w = h3;
        ushort4 lv;
        lv.x = f2bf(v.x - bf2f(h0)); lv.y = f2bf(v.y - bf2f(h1));
        lv.z = f2bf(v.z - bf2f(h2_)); lv.w = f2bf(v.w - bf2f(h3));
        *reinterpret_cast<ushort4*>(&A2[row * AST + kp]) = hv;
        *reinterpret_cast<ushort4*>(&A2[row * AST + 128 + kp]) = lv;
    }
    __syncthreads();

    f32x4 acc[4][2];
    #pragma unroll
    for (int mt = 0; mt < 4; ++mt)
        #pragma unroll
        for (int nt = 0; nt < 2; ++nt)
            acc[mt][nt] = (f32x4){0.f, 0.f, 0.f, 0.f};

    #pragma unroll
    for (int kc = 0; kc < 4; ++kc) {
        bf16x8 ahi[4], alo[4];
        #pragma unroll
        for (int mt = 0; mt < 4; ++mt) {
            ahi[mt] = *reinterpret_cast<const bf16x8*>(&A2[(mt * 16 + l16) * AST + kc * 32 + q * 8]);
            alo[mt] = *reinterpret_cast<const bf16x8*>(&A2[(mt * 16 + l16) * AST + 128 + kc * 32 + q * 8]);
        }
        #pragma unroll
        for (int mt = 0; mt < 4; ++mt)
            #pragma unroll
            for (int nt = 0; nt < 2; ++nt) {
                acc[mt][nt] = __builtin_amdgcn_mfma_f32_16x16x32_bf16(ahi[mt], bh[nt][kc], acc[mt][nt], 0, 0, 0);
                acc[mt][nt] = __builtin_amdgcn_mfma_f32_16x16x32_bf16(ahi[mt], bl[nt][kc], acc[mt][nt], 0, 0, 0);
                acc[mt][nt] = __builtin_amdgcn_mfma_f32_16x16x32_bf16(alo[mt], bh[nt][kc], acc[mt][nt], 0, 0, 0);
            }
    }
    __syncthreads();   // all Kloop1 reads done before A2 overwrite

    // B2 fragments issued FIRST: global-load latency hides under epilogue-1 VALU+LDS
    #pragma unroll
    for (int nt = 0; nt < 2; ++nt) {
        int n = w * 32 + nt * 16 + l16;
        const bf16x8* gh = reinterpret_cast<const bf16x8*>(W2hi + (size_t)n * DIM);
        const bf16x8* gl = reinterpret_cast<const bf16x8*>(W2lo + (size_t)n * DIM);
        #pragma unroll
        for (int kc = 0; kc < 4; ++kc) {
            bh[nt][kc] = gh[kc * 4 + q];
            bl[nt][kc] = gl[kc * 4 + q];
        }
    }

    // epilogue 1: bias + BN1 + ReLU -> back into A2 (hi/lo), local rows
    #pragma unroll
    for (int nt = 0; nt < 2; ++nt) {
        int col = w * 32 + nt * 16 + l16;
        float bias = b1[col];
        float sc = bn1g[col] * rsqrtf(bn1v[col] + BN_EPS);
        float sh = bn1b[col] - bn1m[col] * sc;
        #pragma unroll
        for (int mt = 0; mt < 4; ++mt) {
            #pragma unroll
            for (int r = 0; r < 4; ++r) {
                int rowl = mt * 16 + q * 4 + r;
                float o = fmaxf((acc[mt][nt][r] + bias) * sc + sh, 0.f);
                unsigned short hi = f2bf(o);
                A2[rowl * AST + col] = hi;
                A2[rowl * AST + 128 + col] = f2bf(o - bf2f(hi));
            }
        }
    }
    __syncthreads();

    #pragma unroll
    for (int mt = 0; mt < 4; ++mt)
        #pragma unroll
        for (int nt = 0; nt < 2; ++nt)
            acc[mt][nt] = (f32x4){0.f, 0.f, 0.f, 0.f};

    #pragma unroll
    for (int kc = 0; kc < 4; ++kc) {
        bf16x8 ahi[4], alo[4];
        #pragma unroll
        for (int mt = 0; mt < 4; ++mt) {
            ahi[mt] = *reinterpret_cast<const bf16x8*>(&A2[(mt * 16 + l16) * AST + kc * 32 + q * 8]);
            alo[mt] = *reinterpret_cast<const bf16x8*>(&A2[(mt * 16 + l16) * AST + 128 + kc * 32 + q * 8]);
        }
        #pragma unroll
        for (int mt = 0; mt < 4; ++mt)
            #pragma unroll
            for (int nt = 0; nt < 2; ++nt) {
                acc[mt][nt] = __builtin_amdgcn_mfma_f32_16x16x32_bf16(ahi[mt], bh[nt][kc], acc[mt][nt], 0, 0, 0);
                acc[mt][nt] = __builtin_amdgcn_mfma_f32_16x16x32_bf16(ahi[mt], bl[nt][kc], acc[mt][nt], 0, 0, 0);
                acc[mt][nt] = __builtin_amdgcn_mfma_f32_16x16x32_bf16(alo[mt], bh[nt][kc], acc[mt][nt], 0, 0, 0);
            }
    }

    // epilogue 2: bias + BN2 + ReLU -> x + xb
    #pragma unroll
    for (int nt = 0; nt < 2; ++nt) {
        int col = w * 32 + nt * 16 + l16;
        float bias = b2[col];
        float sc = bn2g[col] * rsqrtf(bn2v[col] + BN_EPS);
        float sh = bn2b[col] - bn2m[col] * sc;
        #pragma unroll
        for (int mt = 0; mt < 4; ++mt) {
            #pragma unroll
            for (int r = 0; r < 4; ++r) {
                int row = r0 + mt * 16 + q * 4 + r;
                float o = fmaxf((acc[mt][nt][r] + bias) * sc + sh, 0.f);
                outx[(size_t)row * DIM + col] = o;
                xb_out[(size_t)row * DIM + col] = f2bf(o);
            }
        }
    }
}

// ---------------- global mean pool (batch sorted) ----------------

__global__ __launch_bounds__(256)
void pool_kernel(const float* __restrict__ x, const int* __restrict__ batch,
                 float* __restrict__ g) {
    __shared__ float sh[256];
    __shared__ int sb[2];
    int gid = blockIdx.x;
    int t = threadIdx.x;
    if (t < 2) {
        int tgt = gid + t;
        int lo = 0, hi = N_NODES;
        while (lo < hi) { int mid = (lo + hi) >> 1; if (batch[mid] < tgt) lo = mid + 1; else hi = mid; }
        sb[t] = lo;
    }
    __syncthreads();
    int lo = sb[0], hi = sb[1];
    int d = t & 127, half = t >> 7;
    float a = 0.f;
    for (int n = lo + half; n < hi; n += 2) a += x[(size_t)n * DIM + d];
    sh[t] = a;
    __syncthreads();
    if (t < DIM) {
        float cnt = fmaxf((float)(hi - lo), 1.f);
        g[gid * DIM + t] = (sh[t] + sh[t + 128]) / cnt;
    }
}

// ---------------- head ----------------

__global__ __launch_bounds__(128)
void head1_kernel(const float* __restrict__ g, const float* __restrict__ W1,
                  const float* __restrict__ b1, float* __restrict__ h1) {
    __shared__ float gs[DIM];
    int gid = blockIdx.x, c = threadIdx.x;
    gs[c] = g[gid * DIM + c];
    __syncthreads();
    float acc = b1[c];
    for (int k = 0; k < DIM; ++k) acc += gs[k] * W1[k * DIM + c];
    h1[gid * DIM + c] = fmaxf(acc, 0.f);
}

__global__ __launch_bounds__(64)
void head2_kernel(const float* __restrict__ h1, const float* __restrict__ W2,
                  const float* __restrict__ b2, float* __restrict__ out) {
    __shared__ float hs[DIM];
    int gid = blockIdx.x;
    int t = threadIdx.x;
    hs[t] = h1[gid * DIM + t];
    hs[t + 64] = h1[gid * DIM + t + 64];
    __syncthreads();
    if (t < NCLASS) {
        float acc = b2[t];
        for (int k = 0; k < DIM; ++k) acc += hs[k] * W2[k * NCLASS + t];
        out[gid * NCLASS + t] = acc;
    }
}

// ---------------- launch ----------------

extern "C" void kernel_launch(void* const* d_in, const int* in_sizes, int n_in,
                              void* d_out, int out_size, void* d_ws, size_t ws_size,
                              hipStream_t stream) {
    const float* edge_attr = (const float*)d_in[0];
    const int*   edge_index = (const int*)d_in[1];
    const int*   batch = (const int*)d_in[2];
    const float* node_emb = (const float*)d_in[3];
    const float* edge_W = (const float*)d_in[4];
    const float* edge_b = (const float*)d_in[5];
    const float* mlp_W1 = (const float*)d_in[6];
    const float* mlp_b1 = (const float*)d_in[7];
    const float* bn1_g = (const float*)d_in[8];
    const float* bn1_b = (const float*)d_in[9];
    const float* bn1_m = (const float*)d_in[10];
    const float* bn1_v = (const float*)d_in[11];
    const float* mlp_W2 = (const float*)d_in[12];
    const float* mlp_b2 = (const float*)d_in[13];
    const float* bn2_g = (const float*)d_in[14];
    const float* bn2_b = (const float*)d_in[15];
    const float* bn2_m = (const float*)d_in[16];
    const float* bn2_v = (const float*)d_in[17];
    const float* head_W1 = (const float*)d_in[18];
    const float* head_b1 = (const float*)d_in[19];
    const float* head_W2 = (const float*)d_in[20];
    const float* head_b2 = (const float*)d_in[21];
    float* out = (float*)d_out;

    const int* src = edge_index;
    const int* dst = edge_index + N_EDGES;

    size_t off = 0;
    auto carve = [&](size_t bytes) {
        void* p = (char*)d_ws + off;
        off += (bytes + 255) & ~(size_t)255;
        return p;
    };
    float* x            = (float*)carve((size_t)N_PAD * DIM * 4);
    unsigned short* xb  = (unsigned short*)carve((size_t)N_PAD * DIM * 2);
    float* h            = (float*)carve((size_t)N_PAD * DIM * 4);
    _Float16* eah       = (_Float16*)carve((size_t)N_EDGES * 8 * 2);
    _Float16* eac       = (_Float16*)carve((size_t)N_EDGES * 8 * 2);
    int* srcc           = (int*)carve((size_t)N_EDGES * 4);
    unsigned short* Wthi = (unsigned short*)carve((size_t)2 * LAYERS * DIM * DIM * 2);
    unsigned short* Wtlo = (unsigned short*)carve((size_t)2 * LAYERS * DIM * DIM * 2);
    int* deg      = (int*)carve((size_t)N_NODES * 4);
    int* row_off  = (int*)carve((size_t)(N_NODES + 1) * 4);
    int* cursor   = (int*)carve((size_t)N_NODES * 4);
    int* csr      = (int*)carve((size_t)N_EDGES * 4);
    int* bsums    = (int*)carve((size_t)NSB * 4);
    float* gbuf   = (float*)carve((size_t)N_GRAPHS * DIM * 4);
    float* h1buf  = (float*)carve((size_t)N_GRAPHS * DIM * 4);
    (void)ws_size;

    // CSR build
    zero_ints<<<(N_NODES + 255) / 256, 256, 0, stream>>>(deg, N_NODES);
    hist_kernel<<<(N_EDGES + 255) / 256, 256, 0, stream>>>(dst, deg);
    scan1<<<NSB, 256, 0, stream>>>(deg, row_off, bsums);
    scan2<<<1, 256, 0, stream>>>(bsums);
    scan3<<<NSB, 256, 0, stream>>>(row_off, bsums, cursor);
    fill_csr<<<(N_EDGES + 255) / 256, 256, 0, stream>>>(dst, cursor, csr);

    init_x<<<(N_NODES * DIM + 255) / 256, 256, 0, stream>>>(x, xb, node_emb);
    prep_ea<<<(N_EDGES * 8 + 255) / 256, 256, 0, stream>>>(edge_attr, eah);
    prep_perm<<<(N_EDGES + 255) / 256, 256, 0, stream>>>(csr, src, eah, srcc, eac);
    prep_w<<<(2 * LAYERS * DIM * DIM + 255) / 256, 256, 0, stream>>>(mlp_W1, mlp_W2, Wthi, Wtlo);

    const int gemm_blocks = N_PAD / TM;   // 782
    for (int l = 0; l < LAYERS; ++l) {
        aggregate<<<N_NODES / 8, 256, 0, stream>>>(
            x, xb, h, eac, srcc, row_off,
            edge_W + (size_t)l * EDIM * DIM, edge_b + (size_t)l * DIM);
        gemm2x<<<gemm_blocks, 256, 0, stream>>>(
            h, x, xb,
            Wthi + ((size_t)l << 14), Wtlo + ((size_t)l << 14),
            Wthi + ((size_t)(LAYERS + l) << 14), Wtlo + ((size_t)(LAYERS + l) << 14),
            mlp_b1 + (size_t)l * DIM,
            bn1_g + (size_t)l * DIM, bn1_b + (size_t)l * DIM,
            bn1_m + (size_t)l * DIM, bn1_v + (size_t)l * DIM,
            mlp_b2 + (size_t)l * DIM,
            bn2_g + (size_t)l * DIM, bn2_b + (size_t)l * DIM,
            bn2_m + (size_t)l * DIM, bn2_v + (size_t)l * DIM);
    }

    pool_kernel<<<N_GRAPHS, 256, 0, stream>>>(x, batch, gbuf);
    head1_kernel<<<N_GRAPHS, 128, 0, stream>>>(gbuf, head_W1, head_b1, h1buf);
    head2_kernel<<<N_GRAPHS, 64, 0, stream>>>(h1buf, head_W2, head_b2, out);
}

// Round 12
// 606.629 us; speedup vs baseline: 4.2402x; 1.0758x over previous
//
#include <hip/hip_runtime.h>

#define N_NODES 50000
#define N_PAD   50048   // multiple of 64; pad rows garbage, never consumed
#define N_EDGES 800000
#define N_GRAPHS 500
#define DIM 128
#define EDIM 7
#define LAYERS 5
#define NCLASS 10
#define BN_EPS 1e-5f
#define TM 64
#define AST 264         // LDS A row stride (ushort): 528 B = odd 16B multiple -> conflict-free b128
#define NSB ((N_NODES + 256) / 256)   // 196 scan blocks
#define NBA 16          // nodes per aggregate block (16 lanes/node, 8 feats/lane)

typedef __attribute__((ext_vector_type(8))) short bf16x8;
typedef __attribute__((ext_vector_type(4))) float f32x4;
typedef _Float16 h2 __attribute__((ext_vector_type(2)));

struct __align__(32) ERec { uint4 ea; int src; int pad0, pad1, pad2; };

__device__ __forceinline__ unsigned short f2bf(float f) {
    unsigned u = __float_as_uint(f);
    u = u + 0x7fffu + ((u >> 16) & 1u);   // RNE
    return (unsigned short)(u >> 16);
}
__device__ __forceinline__ float bf2f(unsigned short h) {
    return __uint_as_float(((unsigned)h) << 16);
}
__device__ __forceinline__ h2 u2h2(unsigned u) {
    union { unsigned u; h2 h; } c; c.u = u; return c.h;
}
__device__ __forceinline__ unsigned h22u(h2 h) {
    union { h2 h; unsigned u; } c; c.h = h; return c.u;
}
__device__ __forceinline__ unsigned packh2(float a, float b) {
    h2 h; h.x = (_Float16)a; h.y = (_Float16)b;   // RNE casts
    return h22u(h);
}

// ---------------- CSR build ----------------

__global__ void zero_ints(int* __restrict__ p, int n) {
    int i = blockIdx.x * 256 + threadIdx.x;
    if (i < n) p[i] = 0;
}

__global__ void hist_kernel(const int* __restrict__ dst, int* __restrict__ deg) {
    int e = blockIdx.x * 256 + threadIdx.x;
    if (e < N_EDGES) atomicAdd(&deg[dst[e]], 1);
}

__global__ __launch_bounds__(256)
void scan1(const int* __restrict__ deg, int* __restrict__ ro, int* __restrict__ bsums) {
    __shared__ int ws[4];
    int t = threadIdx.x;
    int i = blockIdx.x * 256 + t;
    int v = (i < N_NODES) ? deg[i] : 0;
    int lane = t & 63, wv = t >> 6;
    int s = v;
    #pragma unroll
    for (int off = 1; off < 64; off <<= 1) {
        int u = __shfl_up(s, off, 64);
        if (lane >= off) s += u;
    }
    if (lane == 63) ws[wv] = s;
    __syncthreads();
    if (t == 0) {
        int a = 0;
        #pragma unroll
        for (int k = 0; k < 4; ++k) { int x = ws[k]; ws[k] = a; a += x; }
        bsums[blockIdx.x] = a;
    }
    __syncthreads();
    int excl = s - v + ws[wv];
    if (i <= N_NODES) ro[i] = excl;
}

__global__ __launch_bounds__(256)
void scan2(int* __restrict__ bsums) {
    __shared__ int ws[4];
    int t = threadIdx.x;
    int v = (t < NSB) ? bsums[t] : 0;
    int lane = t & 63, wv = t >> 6;
    int s = v;
    #pragma unroll
    for (int off = 1; off < 64; off <<= 1) {
        int u = __shfl_up(s, off, 64);
        if (lane >= off) s += u;
    }
    if (lane == 63) ws[wv] = s;
    __syncthreads();
    if (t == 0) {
        int a = 0;
        #pragma unroll
        for (int k = 0; k < 4; ++k) { int x = ws[k]; ws[k] = a; a += x; }
    }
    __syncthreads();
    if (t < NSB) bsums[t] = s - v + ws[wv];
}

__global__ __launch_bounds__(256)
void scan3(int* __restrict__ ro, const int* __restrict__ bsums, int* __restrict__ cursor) {
    int i = blockIdx.x * 256 + threadIdx.x;
    if (i <= N_NODES) {
        int r = ro[i] + bsums[i >> 8];
        ro[i] = r;
        if (i < N_NODES) cursor[i] = r;
    }
}

// single pass: sequential read of src/dst/edge_attr, fp16 conversion, one
// scattered 32B record store per edge (replaces fill_csr + prep_ea + prep_perm)
__global__ void fill_rec(const int* __restrict__ dst, const int* __restrict__ src,
                         const float* __restrict__ edge_attr,
                         int* __restrict__ cursor, ERec* __restrict__ rec) {
    int e = blockIdx.x * 256 + threadIdx.x;
    if (e < N_EDGES) {
        const float* ap = edge_attr + (size_t)e * EDIM;
        uint4 ea;
        ea.x = packh2(ap[0], ap[1]);
        ea.y = packh2(ap[2], ap[3]);
        ea.z = packh2(ap[4], ap[5]);
        ea.w = packh2(ap[6], 0.f);
        int s = src[e];
        int pos = atomicAdd(&cursor[dst[e]], 1);
        rec[pos].ea = ea;
        rec[pos].src = s;
    }
}

// ---------------- one-time preps ----------------

__global__ void init_x(float* __restrict__ x, unsigned short* __restrict__ xb,
                       const float* __restrict__ emb) {
    int i = blockIdx.x * 256 + threadIdx.x;
    if (i < N_NODES * DIM) {
        float v = emb[i & (DIM - 1)];
        x[i] = v;
        xb[i] = f2bf(v);
    }
}

// W [k][n] fp32 -> transposed hi/lo bf16 Wt[m][n][k]
__global__ void prep_w(const float* __restrict__ W1, const float* __restrict__ W2,
                       unsigned short* __restrict__ Wthi, unsigned short* __restrict__ Wtlo) {
    int i = blockIdx.x * 256 + threadIdx.x;
    if (i >= 2 * LAYERS * DIM * DIM) return;
    int m = i >> 14;
    int n = i & 127;
    int k = (i >> 7) & 127;
    const float* W = (m < LAYERS) ? (W1 + (size_t)m * DIM * DIM)
                                  : (W2 + (size_t)(m - LAYERS) * DIM * DIM);
    float v = W[k * DIM + n];
    unsigned short hi = f2bf(v);
    float lo = v - bf2f(hi);
    size_t o = ((size_t)m << 14) + (size_t)n * DIM + k;
    Wthi[o] = hi;
    Wtlo[o] = f2bf(lo);
}

// ---------------- aggregation ----------------
// 16 nodes/256-block, 16 lanes/node, 8 feats/lane: per-edge loop overhead is
// shared by half the lanes vs the 32-lane layout. Edge linear = 32 fdot2/lane.
// rec[] is CSR-ordered -> sequential; only the xb gather is random.

#if __has_builtin(__builtin_amdgcn_fdot2)
#define HAVE_FDOT2 1
#else
#define HAVE_FDOT2 0
#endif

__device__ __forceinline__ void edge_accum8(float4& acc0, float4& acc1,
                                            uint4 eav, uint4 xv,
                                            const unsigned* Wp,
                                            const float4& b0, const float4& b1) {
    float el[8] = {b0.x, b0.y, b0.z, b0.w, b1.x, b1.y, b1.z, b1.w};
#if HAVE_FDOT2
    #pragma unroll
    for (int d = 0; d < 8; ++d) {
        float e = el[d];
        e = __builtin_amdgcn_fdot2(u2h2(eav.x), u2h2(Wp[d * 4 + 0]), e, false);
        e = __builtin_amdgcn_fdot2(u2h2(eav.y), u2h2(Wp[d * 4 + 1]), e, false);
        e = __builtin_amdgcn_fdot2(u2h2(eav.z), u2h2(Wp[d * 4 + 2]), e, false);
        e = __builtin_amdgcn_fdot2(u2h2(eav.w), u2h2(Wp[d * 4 + 3]), e, false);
        el[d] = e;
    }
#else
    h2 ea01 = u2h2(eav.x), ea23 = u2h2(eav.y), ea45 = u2h2(eav.z), ea67 = u2h2(eav.w);
    float a[8] = {(float)ea01.x, (float)ea01.y, (float)ea23.x, (float)ea23.y,
                  (float)ea45.x, (float)ea45.y, (float)ea67.x, 0.f};
    #pragma unroll
    for (int d = 0; d < 8; ++d) {
        float e = el[d];
        #pragma unroll
        for (int kp = 0; kp < 4; ++kp) {
            h2 w = u2h2(Wp[d * 4 + kp]);
            e += a[kp * 2] * (float)w.x + a[kp * 2 + 1] * (float)w.y;
        }
        el[d] = e;
    }
#endif
    acc0.x += fmaxf(__uint_as_float(xv.x << 16)         + el[0], 0.f);
    acc0.y += fmaxf(__uint_as_float(xv.x & 0xffff0000u) + el[1], 0.f);
    acc0.z += fmaxf(__uint_as_float(xv.y << 16)         + el[2], 0.f);
    acc0.w += fmaxf(__uint_as_float(xv.y & 0xffff0000u) + el[3], 0.f);
    acc1.x += fmaxf(__uint_as_float(xv.z << 16)         + el[4], 0.f);
    acc1.y += fmaxf(__uint_as_float(xv.z & 0xffff0000u) + el[5], 0.f);
    acc1.z += fmaxf(__uint_as_float(xv.w << 16)         + el[6], 0.f);
    acc1.w += fmaxf(__uint_as_float(xv.w & 0xffff0000u) + el[7], 0.f);
}

__global__ __launch_bounds__(256, 4)
void aggregate(const float* __restrict__ x, const unsigned short* __restrict__ xb,
               float* __restrict__ h,
               const ERec* __restrict__ rec,
               const int* __restrict__ row_off,
               const float* __restrict__ eW, const float* __restrict__ eb) {
    int t = threadIdx.x;
    int nl = t >> 4, lane = t & 15, c0 = lane * 8;
    int n = blockIdx.x * NBA + nl;

    // Wp[d*4+kp] = (W[2kp][c0+d], W[2kp+1][c0+d]) as fp16 pair; k=7 padded 0
    unsigned Wp[32];
    #pragma unroll
    for (int d = 0; d < 8; ++d) {
        #pragma unroll
        for (int kp = 0; kp < 4; ++kp) {
            float w0 = eW[(kp * 2) * DIM + c0 + d];
            float w1 = (kp * 2 + 1 < EDIM) ? eW[(kp * 2 + 1) * DIM + c0 + d] : 0.f;
            Wp[d * 4 + kp] = packh2(w0, w1);
        }
    }
    float4 b0 = *reinterpret_cast<const float4*>(eb + c0);
    float4 b1 = *reinterpret_cast<const float4*>(eb + c0 + 4);
    #pragma unroll
    for (int k = 0; k < 32; ++k) asm volatile("" : "+v"(Wp[k]));
    asm volatile("" : "+v"(b0.x), "+v"(b0.y), "+v"(b0.z), "+v"(b0.w));
    asm volatile("" : "+v"(b1.x), "+v"(b1.y), "+v"(b1.z), "+v"(b1.w));

    float4 acc0 = *reinterpret_cast<const float4*>(x + (size_t)n * DIM + c0);
    float4 acc1 = *reinterpret_cast<const float4*>(x + (size_t)n * DIM + c0 + 4);
    int idx = row_off[n], end = row_off[n + 1];

    int s_c[4];
    bool have = (idx + 4 <= end);
    if (have) {
        #pragma unroll
        for (int j = 0; j < 4; ++j) s_c[j] = rec[idx + j].src;
    }
    while (have) {
        uint4 ea[4], xv[4];
        #pragma unroll
        for (int j = 0; j < 4; ++j) ea[j] = rec[idx + j].ea;
        #pragma unroll
        for (int j = 0; j < 4; ++j) xv[j] = *reinterpret_cast<const uint4*>(xb + (size_t)s_c[j] * DIM + c0);
        idx += 4;
        bool nxt = (idx + 4 <= end);
        int s_n[4];
        if (nxt) {
            #pragma unroll
            for (int j = 0; j < 4; ++j) s_n[j] = rec[idx + j].src;
        }
        #pragma unroll
        for (int j = 0; j < 4; ++j) edge_accum8(acc0, acc1, ea[j], xv[j], Wp, b0, b1);
        if (nxt) {
            #pragma unroll
            for (int j = 0; j < 4; ++j) s_c[j] = s_n[j];
        }
        have = nxt;
    }
    for (; idx < end; ++idx) {
        int s = rec[idx].src;
        uint4 ea = rec[idx].ea;
        uint4 xv = *reinterpret_cast<const uint4*>(xb + (size_t)s * DIM + c0);
        edge_accum8(acc0, acc1, ea, xv, Wp, b0, b1);
    }
    *reinterpret_cast<float4*>(h + (size_t)n * DIM + c0) = acc0;
    *reinterpret_cast<float4*>(h + (size_t)n * DIM + c0 + 4) = acc1;
}

// ---------------- fused double MFMA GEMM: x = bn2relu( bn1relu(h@W1+b1) @ W2 + b2 ) ----------------

__global__ __launch_bounds__(256)
void gemm2x(const float* __restrict__ in, float* __restrict__ outx,
            unsigned short* __restrict__ xb_out,
            const unsigned short* __restrict__ W1hi, const unsigned short* __restrict__ W1lo,
            const unsigned short* __restrict__ W2hi, const unsigned short* __restrict__ W2lo,
            const float* __restrict__ b1,
            const float* __restrict__ bn1g, const float* __restrict__ bn1b,
            const float* __restrict__ bn1m, const float* __restrict__ bn1v,
            const float* __restrict__ b2,
            const float* __restrict__ bn2g, const float* __restrict__ bn2b,
            const float* __restrict__ bn2m, const float* __restrict__ bn2v) {
    __shared__ __align__(16) unsigned short A2[TM * AST];   // 33792 B
    int t = threadIdx.x;
    int r0 = blockIdx.x * TM;
    int w = t >> 6;
    int lane = t & 63;
    int q = lane >> 4;
    int l16 = lane & 15;

    // B1 register fragments (in flight during A staging)
    bf16x8 bh[2][4], bl[2][4];
    #pragma unroll
    for (int nt = 0; nt < 2; ++nt) {
        int n = w * 32 + nt * 16 + l16;
        const bf16x8* gh = reinterpret_cast<const bf16x8*>(W1hi + (size_t)n * DIM);
        const bf16x8* gl = reinterpret_cast<const bf16x8*>(W1lo + (size_t)n * DIM);
        #pragma unroll
        for (int kc = 0; kc < 4; ++kc) {
            bh[nt][kc] = gh[kc * 4 + q];
            bl[nt][kc] = gl[kc * 4 + q];
        }
    }

    // stage A (hi/lo split)
    #pragma unroll
    for (int i = 0; i < 8; ++i) {
        int idx = t + i * 256;
        int row = idx >> 5;
        int kp = (idx & 31) * 4;
        float4 v = reinterpret_cast<const float4*>(in + (size_t)r0 * DIM)[idx];
        unsigned short h0 = f2bf(v.x), h1 = f2bf(v.y), h2_ = f2bf(v.z), h3 = f2bf(v.w);
        ushort4 hv; hv.x = h0; hv.y = h1; hv.z = h2_; hv.w = h3;
        ushort4 lv;
        lv.x = f2bf(v.x - bf2f(h0)); lv.y = f2bf(v.y - bf2f(h1));
        lv.z = f2bf(v.z - bf2f(h2_)); lv.w = f2bf(v.w - bf2f(h3));
        *reinterpret_cast<ushort4*>(&A2[row * AST + kp]) = hv;
        *reinterpret_cast<ushort4*>(&A2[row * AST + 128 + kp]) = lv;
    }
    __syncthreads();

    f32x4 acc[4][2];
    #pragma unroll
    for (int mt = 0; mt < 4; ++mt)
        #pragma unroll
        for (int nt = 0; nt < 2; ++nt)
            acc[mt][nt] = (f32x4){0.f, 0.f, 0.f, 0.f};

    #pragma unroll
    for (int kc = 0; kc < 4; ++kc) {
        bf16x8 ahi[4], alo[4];
        #pragma unroll
        for (int mt = 0; mt < 4; ++mt) {
            ahi[mt] = *reinterpret_cast<const bf16x8*>(&A2[(mt * 16 + l16) * AST + kc * 32 + q * 8]);
            alo[mt] = *reinterpret_cast<const bf16x8*>(&A2[(mt * 16 + l16) * AST + 128 + kc * 32 + q * 8]);
        }
        #pragma unroll
        for (int mt = 0; mt < 4; ++mt)
            #pragma unroll
            for (int nt = 0; nt < 2; ++nt) {
                acc[mt][nt] = __builtin_amdgcn_mfma_f32_16x16x32_bf16(ahi[mt], bh[nt][kc], acc[mt][nt], 0, 0, 0);
                acc[mt][nt] = __builtin_amdgcn_mfma_f32_16x16x32_bf16(ahi[mt], bl[nt][kc], acc[mt][nt], 0, 0, 0);
                acc[mt][nt] = __builtin_amdgcn_mfma_f32_16x16x32_bf16(alo[mt], bh[nt][kc], acc[mt][nt], 0, 0, 0);
            }
    }
    __syncthreads();   // all Kloop1 reads done before A2 overwrite

    // B2 fragments issued FIRST: global-load latency hides under epilogue-1 VALU+LDS
    #pragma unroll
    for (int nt = 0; nt < 2; ++nt) {
        int n = w * 32 + nt * 16 + l16;
        const bf16x8* gh = reinterpret_cast<const bf16x8*>(W2hi + (size_t)n * DIM);
        const bf16x8* gl = reinterpret_cast<const bf16x8*>(W2lo + (size_t)n * DIM);
        #pragma unroll
        for (int kc = 0; kc < 4; ++kc) {
            bh[nt][kc] = gh[kc * 4 + q];
            bl[nt][kc] = gl[kc * 4 + q];
        }
    }

    // epilogue 1: bias + BN1 + ReLU -> back into A2 (hi/lo), local rows
    #pragma unroll
    for (int nt = 0; nt < 2; ++nt) {
        int col = w * 32 + nt * 16 + l16;
        float bias = b1[col];
        float sc = bn1g[col] * rsqrtf(bn1v[col] + BN_EPS);
        float sh = bn1b[col] - bn1m[col] * sc;
        #pragma unroll
        for (int mt = 0; mt < 4; ++mt) {
            #pragma unroll
            for (int r = 0; r < 4; ++r) {
                int rowl = mt * 16 + q * 4 + r;
                float o = fmaxf((acc[mt][nt][r] + bias) * sc + sh, 0.f);
                unsigned short hi = f2bf(o);
                A2[rowl * AST + col] = hi;
                A2[rowl * AST + 128 + col] = f2bf(o - bf2f(hi));
            }
        }
    }
    __syncthreads();

    #pragma unroll
    for (int mt = 0; mt < 4; ++mt)
        #pragma unroll
        for (int nt = 0; nt < 2; ++nt)
            acc[mt][nt] = (f32x4){0.f, 0.f, 0.f, 0.f};

    #pragma unroll
    for (int kc = 0; kc < 4; ++kc) {
        bf16x8 ahi[4], alo[4];
        #pragma unroll
        for (int mt = 0; mt < 4; ++mt) {
            ahi[mt] = *reinterpret_cast<const bf16x8*>(&A2[(mt * 16 + l16) * AST + kc * 32 + q * 8]);
            alo[mt] = *reinterpret_cast<const bf16x8*>(&A2[(mt * 16 + l16) * AST + 128 + kc * 32 + q * 8]);
        }
        #pragma unroll
        for (int mt = 0; mt < 4; ++mt)
            #pragma unroll
            for (int nt = 0; nt < 2; ++nt) {
                acc[mt][nt] = __builtin_amdgcn_mfma_f32_16x16x32_bf16(ahi[mt], bh[nt][kc], acc[mt][nt], 0, 0, 0);
                acc[mt][nt] = __builtin_amdgcn_mfma_f32_16x16x32_bf16(ahi[mt], bl[nt][kc], acc[mt][nt], 0, 0, 0);
                acc[mt][nt] = __builtin_amdgcn_mfma_f32_16x16x32_bf16(alo[mt], bh[nt][kc], acc[mt][nt], 0, 0, 0);
            }
    }

    // epilogue 2: bias + BN2 + ReLU -> x + xb
    #pragma unroll
    for (int nt = 0; nt < 2; ++nt) {
        int col = w * 32 + nt * 16 + l16;
        float bias = b2[col];
        float sc = bn2g[col] * rsqrtf(bn2v[col] + BN_EPS);
        float sh = bn2b[col] - bn2m[col] * sc;
        #pragma unroll
        for (int mt = 0; mt < 4; ++mt) {
            #pragma unroll
            for (int r = 0; r < 4; ++r) {
                int row = r0 + mt * 16 + q * 4 + r;
                float o = fmaxf((acc[mt][nt][r] + bias) * sc + sh, 0.f);
                outx[(size_t)row * DIM + col] = o;
                xb_out[(size_t)row * DIM + col] = f2bf(o);
            }
        }
    }
}

// ---------------- global mean pool (batch sorted) ----------------

__global__ __launch_bounds__(256)
void pool_kernel(const float* __restrict__ x, const int* __restrict__ batch,
                 float* __restrict__ g) {
    __shared__ float sh[256];
    __shared__ int sb[2];
    int gid = blockIdx.x;
    int t = threadIdx.x;
    if (t < 2) {
        int tgt = gid + t;
        int lo = 0, hi = N_NODES;
        while (lo < hi) { int mid = (lo + hi) >> 1; if (batch[mid] < tgt) lo = mid + 1; else hi = mid; }
        sb[t] = lo;
    }
    __syncthreads();
    int lo = sb[0], hi = sb[1];
    int d = t & 127, half = t >> 7;
    float a = 0.f;
    for (int n = lo + half; n < hi; n += 2) a += x[(size_t)n * DIM + d];
    sh[t] = a;
    __syncthreads();
    if (t < DIM) {
        float cnt = fmaxf((float)(hi - lo), 1.f);
        g[gid * DIM + t] = (sh[t] + sh[t + 128]) / cnt;
    }
}

// ---------------- head ----------------

__global__ __launch_bounds__(128)
void head1_kernel(const float* __restrict__ g, const float* __restrict__ W1,
                  const float* __restrict__ b1, float* __restrict__ h1) {
    __shared__ float gs[DIM];
    int gid = blockIdx.x, c = threadIdx.x;
    gs[c] = g[gid * DIM + c];
    __syncthreads();
    float acc = b1[c];
    for (int k = 0; k < DIM; ++k) acc += gs[k] * W1[k * DIM + c];
    h1[gid * DIM + c] = fmaxf(acc, 0.f);
}

__global__ __launch_bounds__(64)
void head2_kernel(const float* __restrict__ h1, const float* __restrict__ W2,
                  const float* __restrict__ b2, float* __restrict__ out) {
    __shared__ float hs[DIM];
    int gid = blockIdx.x;
    int t = threadIdx.x;
    hs[t] = h1[gid * DIM + t];
    hs[t + 64] = h1[gid * DIM + t + 64];
    __syncthreads();
    if (t < NCLASS) {
        float acc = b2[t];
        for (int k = 0; k < DIM; ++k) acc += hs[k] * W2[k * NCLASS + t];
        out[gid * NCLASS + t] = acc;
    }
}

// ---------------- launch ----------------

extern "C" void kernel_launch(void* const* d_in, const int* in_sizes, int n_in,
                              void* d_out, int out_size, void* d_ws, size_t ws_size,
                              hipStream_t stream) {
    const float* edge_attr = (const float*)d_in[0];
    const int*   edge_index = (const int*)d_in[1];
    const int*   batch = (const int*)d_in[2];
    const float* node_emb = (const float*)d_in[3];
    const float* edge_W = (const float*)d_in[4];
    const float* edge_b = (const float*)d_in[5];
    const float* mlp_W1 = (const float*)d_in[6];
    const float* mlp_b1 = (const float*)d_in[7];
    const float* bn1_g = (const float*)d_in[8];
    const float* bn1_b = (const float*)d_in[9];
    const float* bn1_m = (const float*)d_in[10];
    const float* bn1_v = (const float*)d_in[11];
    const float* mlp_W2 = (const float*)d_in[12];
    const float* mlp_b2 = (const float*)d_in[13];
    const float* bn2_g = (const float*)d_in[14];
    const float* bn2_b = (const float*)d_in[15];
    const float* bn2_m = (const float*)d_in[16];
    const float* bn2_v = (const float*)d_in[17];
    const float* head_W1 = (const float*)d_in[18];
    const float* head_b1 = (const float*)d_in[19];
    const float* head_W2 = (const float*)d_in[20];
    const float* head_b2 = (const float*)d_in[21];
    float* out = (float*)d_out;

    const int* src = edge_index;
    const int* dst = edge_index + N_EDGES;

    size_t off = 0;
    auto carve = [&](size_t bytes) {
        void* p = (char*)d_ws + off;
        off += (bytes + 255) & ~(size_t)255;
        return p;
    };
    float* x            = (float*)carve((size_t)N_PAD * DIM * 4);
    unsigned short* xb  = (unsigned short*)carve((size_t)N_PAD * DIM * 2);
    float* h            = (float*)carve((size_t)N_PAD * DIM * 4);
    ERec* rec           = (ERec*)carve((size_t)N_EDGES * sizeof(ERec));
    unsigned short* Wthi = (unsigned short*)carve((size_t)2 * LAYERS * DIM * DIM * 2);
    unsigned short* Wtlo = (unsigned short*)carve((size_t)2 * LAYERS * DIM * DIM * 2);
    int* deg      = (int*)carve((size_t)N_NODES * 4);
    int* row_off  = (int*)carve((size_t)(N_NODES + 1) * 4);
    int* cursor   = (int*)carve((size_t)N_NODES * 4);
    int* bsums    = (int*)carve((size_t)NSB * 4);
    float* gbuf   = (float*)carve((size_t)N_GRAPHS * DIM * 4);
    float* h1buf  = (float*)carve((size_t)N_GRAPHS * DIM * 4);
    (void)ws_size;

    // CSR build + single-pass edge-record scatter
    zero_ints<<<(N_NODES + 255) / 256, 256, 0, stream>>>(deg, N_NODES);
    hist_kernel<<<(N_EDGES + 255) / 256, 256, 0, stream>>>(dst, deg);
    scan1<<<NSB, 256, 0, stream>>>(deg, row_off, bsums);
    scan2<<<1, 256, 0, stream>>>(bsums);
    scan3<<<NSB, 256, 0, stream>>>(row_off, bsums, cursor);
    fill_rec<<<(N_EDGES + 255) / 256, 256, 0, stream>>>(dst, src, edge_attr, cursor, rec);

    init_x<<<(N_NODES * DIM + 255) / 256, 256, 0, stream>>>(x, xb, node_emb);
    prep_w<<<(2 * LAYERS * DIM * DIM + 255) / 256, 256, 0, stream>>>(mlp_W1, mlp_W2, Wthi, Wtlo);

    const int gemm_blocks = N_PAD / TM;   // 782
    for (int l = 0; l < LAYERS; ++l) {
        aggregate<<<N_NODES / NBA, 256, 0, stream>>>(
            x, xb, h, rec, row_off,
            edge_W + (size_t)l * EDIM * DIM, edge_b + (size_t)l * DIM);
        gemm2x<<<gemm_blocks, 256, 0, stream>>>(
            h, x, xb,
            Wthi + ((size_t)l << 14), Wtlo + ((size_t)l << 14),
            Wthi + ((size_t)(LAYERS + l) << 14), Wtlo + ((size_t)(LAYERS + l) << 14),
            mlp_b1 + (size_t)l * DIM,
            bn1_g + (size_t)l * DIM, bn1_b + (size_t)l * DIM,
            bn1_m + (size_t)l * DIM, bn1_v + (size_t)l * DIM,
            mlp_b2 + (size_t)l * DIM,
            bn2_g + (size_t)l * DIM, bn2_b + (size_t)l * DIM,
            bn2_m + (size_t)l * DIM, bn2_v + (size_t)l * DIM);
    }

    pool_kernel<<<N_GRAPHS, 256, 0, stream>>>(x, batch, gbuf);
    head1_kernel<<<N_GRAPHS, 128, 0, stream>>>(gbuf, head_W1, head_b1, h1buf);
    head2_kernel<<<N_GRAPHS, 64, 0, stream>>>(h1buf, head_W2, head_b2, out);
}